// Round 16
// baseline (265.788 us; speedup 1.0000x reference)
//
#include <hip/hip_runtime.h>
#include <hip/hip_bf16.h>

// Problem constants
#define B_   16
#define L_   512
#define M_   32
#define P_   64
#define D_   128
#define NH_  8
#define NL_  2
#define E_   16
#define EH_  512
#define O_   128

// TCN: full sequence per block, 1024 threads, swizzled LDS, single-W prefetch
#define PADF  16
#define ROWSF 528   // PADF + 512 (32 n-tiles)
#define LDW   64

typedef short  bf16x8 __attribute__((ext_vector_type(8)));
typedef float  f32x4  __attribute__((ext_vector_type(4)));
typedef unsigned short us4 __attribute__((ext_vector_type(4)));
typedef unsigned short us8 __attribute__((ext_vector_type(8)));

__device__ __forceinline__ float bf2f(unsigned short h) {
  unsigned u = ((unsigned)h) << 16; float f; __builtin_memcpy(&f, &u, 4); return f;
}
__device__ __forceinline__ unsigned short f2bf(float f) {
  unsigned u; __builtin_memcpy(&u, &f, 4);
  u += 0x7fffu + ((u >> 16) & 1);
  return (unsigned short)(u >> 16);
}
__device__ __forceinline__ int swz(int row, int col_us) {
  return row * LDW + (col_us ^ ((row & 7) << 3));
}

// xfw packed-buffer offsets (bf16 elements)
#define XFW_PPW   0
#define XFW_QKVO  8192
#define XFW_F1    139264
#define XFW_F2    204800

// ---------------------------------------------------------------------------
// Kernel 0: prep — transposes f32->bf16 + conv wpack + PE table + zero yall
// ---------------------------------------------------------------------------
__global__ __launch_bounds__(256) void prep_kernel(
    const float* __restrict__ ppw,
    const float* __restrict__ twq, const float* __restrict__ twk,
    const float* __restrict__ twv, const float* __restrict__ two,
    const float* __restrict__ f1w, const float* __restrict__ f2w,
    const float* __restrict__ ew1, const float* __restrict__ ew2,
    const float* __restrict__ tw1, const float* __restrict__ tw2,
    unsigned short* __restrict__ xfw, unsigned short* __restrict__ w1t,
    unsigned short* __restrict__ w2t, unsigned short* __restrict__ wpack,
    float* __restrict__ peT, float* __restrict__ yall, int* __restrict__ ecnt) {
  const int b = blockIdx.x;
  const int tid = threadIdx.x;
  if (b < 834) {
    __shared__ float tl[64][65];
    const float* src; unsigned short* dst; int R, C, tr, tc;
    if (b < 2) {
      src = ppw; dst = xfw + XFW_PPW; R = 64; C = 128; tr = 0; tc = b;
    } else if (b < 34) {
      int t = b - 2; int lg = t >> 2; int l = lg >> 2, gem = lg & 3;
      int tt = t & 3; tr = tt >> 1; tc = tt & 1;
      const float* s4 = (gem == 0) ? twq : (gem == 1) ? twk : (gem == 2) ? twv : two;
      src = s4 + l * 16384; dst = xfw + XFW_QKVO + l * 65536 + gem * 16384; R = 128; C = 128;
    } else if (b < 50) {
      int t = b - 34; int l = t >> 3; int tt = t & 7; tr = tt >> 2; tc = tt & 3;
      src = f1w + l * 32768; dst = xfw + XFW_F1 + l * 32768; R = 128; C = 256;
    } else if (b < 66) {
      int t = b - 50; int l = t >> 3; int tt = t & 7; tr = tt >> 1; tc = tt & 1;
      src = f2w + l * 32768; dst = xfw + XFW_F2 + l * 32768; R = 256; C = 128;
    } else if (b < 578) {
      int t = b - 66; int e = t >> 5; int tt = t & 31; tr = tt >> 3; tc = tt & 7;
      src = ew1 + e * 131072; dst = w1t + e * 131072; R = 256; C = 512;
    } else {
      int t = b - 578; int e = t >> 4; int tt = t & 15; tr = tt >> 1; tc = tt & 1;
      src = ew2 + e * 65536; dst = w2t + e * 65536; R = 512; C = 128;
    }
    for (int i = tid; i < 4096; i += 256) {
      int r = i >> 6, c = i & 63;
      tl[r][c] = src[(tr * 64 + r) * C + tc * 64 + c];
    }
    __syncthreads();
    for (int i = tid; i < 4096; i += 256) {
      int c = i >> 6, r = i & 63;
      dst[(tc * 64 + c) * R + tr * 64 + r] = f2bf(tl[r][c]);
    }
  } else if (b < 840) {
    int base = (b - 834) * 16384;
    for (int q = tid; q < 16384; q += 256) {
      int i = base + q;
      int c = i & 63, o = (i >> 6) & 63, tlc = i >> 12;
      int t = tlc % 3, lc = tlc / 3, lvl = lc >> 1;
      const float* src = (lc & 1) ? tw2 : tw1;
      wpack[i] = f2bf(src[lvl * 12288 + o * 192 + c * 3 + t]);
    }
  } else if (b < 842) {
    int base = (b - 840) * 16384;
    for (int q = tid; q < 16384; q += 256) {
      int j = base + q; int ll = j >> 6, c = j & 63;
      float dv = expf(-0.14391157f * (float)(c & ~1));
      float ang = (float)ll * dv;
      peT[j] = (c & 1) ? cosf(ang) : sinf(ang);
    }
  } else {
    int j = b - 842;
    if (j < 68) {
      for (int q = tid; q < 1024; q += 256) yall[j * 1024 + q] = 0.f;
    } else {
      if (tid < 16) ecnt[tid] = 0;
    }
  }
}

// ---------------------------------------------------------------------------
// Kernel 1: TCN — full sequence per block, 1024 threads, single-W prefetch
// phase: {Af->regs; light barrier; WSTORE(next)+WLOAD(next+1) || conv; barrier}
// ---------------------------------------------------------------------------
template <int DIL, bool RES>
__device__ __forceinline__ void conv_phase(const unsigned short* __restrict__ IN,
                                           unsigned short* __restrict__ OUT,
                                           unsigned short* __restrict__ Wb,
                                           const float* __restrict__ bias,
                                           float4* wreg, bool do_store,
                                           const unsigned short* __restrict__ wload) {
  const int tid  = threadIdx.x;
  const int wid  = tid >> 6;        // 16 waves
  const int lane = tid & 63;
  const int fr   = lane & 15;
  const int g    = lane >> 4;
  const int ot0  = (wid & 1) * 2;   // 2 o-tiles per wave
  const int ng   = wid >> 1;        // 8 n-groups; nt = ng + 8k, k<4

  bf16x8 Af[2][6];
#pragma unroll
  for (int oo = 0; oo < 2; ++oo)
#pragma unroll
    for (int t = 0; t < 3; ++t)
#pragma unroll
      for (int kh = 0; kh < 2; ++kh) {
        int wr = t * 64 + (ot0 + oo) * 16 + fr;
        Af[oo][t * 2 + kh] = *(const bf16x8*)(Wb + swz(wr, kh * 32 + g * 8));
      }
  float bv[2][4];
#pragma unroll
  for (int oo = 0; oo < 2; ++oo)
#pragma unroll
    for (int j = 0; j < 4; ++j) bv[oo][j] = bias[(ot0 + oo) * 16 + g * 4 + j];

  __syncthreads();   // Af fragments consumed by all waves -> Wb reusable

  if (do_store) {
    *(float4*)(Wb + swz(tid >> 3, (tid & 7) * 8)) = wreg[0];
    if (tid < 512)
      *(float4*)(Wb + swz((tid >> 3) + 128, (tid & 7) * 8)) = wreg[1];
  }
  if (wload) {
    wreg[0] = *(const float4*)(wload + (tid >> 3) * 64 + (tid & 7) * 8);
    if (tid < 512)
      wreg[1] = *(const float4*)(wload + ((tid >> 3) + 128) * 64 + (tid & 7) * 8);
  }

#pragma unroll
  for (int k = 0; k < 4; ++k) {
    const int rb = PADF + (ng + k * 8) * 16 + fr;
    bf16x8 Bf[6];
#pragma unroll
    for (int t = 0; t < 3; ++t) {
      int r = rb + (t - 2) * DIL;   // causal taps at l-2d, l-d, l
#pragma unroll
      for (int kh = 0; kh < 2; ++kh)
        Bf[t * 2 + kh] = *(const bf16x8*)(IN + swz(r, kh * 32 + g * 8));
    }
    f32x4 acc[2];
#pragma unroll
    for (int oo = 0; oo < 2; ++oo) {
      f32x4 a; a[0] = bv[oo][0]; a[1] = bv[oo][1]; a[2] = bv[oo][2]; a[3] = bv[oo][3];
      acc[oo] = a;
    }
#pragma unroll
    for (int f = 0; f < 6; ++f)
#pragma unroll
      for (int oo = 0; oo < 2; ++oo)
        acc[oo] = __builtin_amdgcn_mfma_f32_16x16x32_bf16(Af[oo][f], Bf[f], acc[oo], 0, 0, 0);

#pragma unroll
    for (int oo = 0; oo < 2; ++oo) {
      unsigned short* op = OUT + swz(rb, (ot0 + oo) * 16 + g * 4);
      us4 old;
      if (RES) old = *(const us4*)op;
      us4 st;
#pragma unroll
      for (int j = 0; j < 4; ++j) {
        float v = fmaxf(acc[oo][j], 0.f);
        if (RES) v = fmaxf(v + bf2f(old[j]), 0.f);
        st[j] = f2bf(v);
      }
      *(us4*)op = st;
    }
  }
  __syncthreads();   // OUT complete + next W ready
}

__global__ __attribute__((amdgpu_flat_work_group_size(1024, 1024),
                          amdgpu_waves_per_eu(4, 4)))
void tcn_kernel(
    const float* __restrict__ x, const float* __restrict__ mask,
    const float* __restrict__ pw, const float* __restrict__ pb,
    const unsigned short* __restrict__ wpack,
    const float* __restrict__ b1, const float* __restrict__ b2,
    const float* __restrict__ peT,
    const float* __restrict__ lng, const float* __restrict__ lnb,
    float* __restrict__ psum) {
  extern __shared__ unsigned short smu[];
  unsigned short* A  = smu;                   // [528][64] bf16 swizzled
  unsigned short* Bq = A + ROWSF * LDW;       // [528][64]
  unsigned short* Wb = Bq + ROWSF * LDW;      // [192][64]
  float* pwpb = (float*)(Wb + 192 * LDW);     // 128 f
  float* mst  = (float*)Wb;                   // overlay after convs: mu|rstd [1024]
  float* pp   = mst + 1024;                   // overlay: pool partials [1024]

  const int seq = blockIdx.x;
  const int b = seq >> 5;
  const int m = seq & 31;
  if (mask[b * M_ + m] == 0.0f) return;       // masked sensor: output unused
  const int tid = threadIdx.x;

  float4 wreg[2];
  // prologue: wreg <- conv0 weights
  wreg[0] = *(const float4*)(wpack + (tid >> 3) * 64 + (tid & 7) * 8);
  if (tid < 512)
    wreg[1] = *(const float4*)(wpack + ((tid >> 3) + 128) * 64 + (tid & 7) * 8);
  if (tid < 64)       pwpb[tid] = pw[tid];
  else if (tid < 128) pwpb[tid] = pb[tid - 64];
  __syncthreads();

  // A-build: one row per thread (tid<528); pad rows of A and Bq zeroed
  if (tid < ROWSF) {
    int r = tid;
    if (r >= PADF) {
      int l = r - PADF;
      float xv = x[(b * L_ + l) * M_ + m];
      const float4* pe4 = (const float4*)(peT + l * 64);
#pragma unroll
      for (int c0 = 0; c0 < 64; c0 += 8) {
        float4 pa = pe4[c0 / 4], pc = pe4[c0 / 4 + 1];
        float pe[8] = {pa.x, pa.y, pa.z, pa.w, pc.x, pc.y, pc.z, pc.w};
        us8 st;
#pragma unroll
        for (int j = 0; j < 8; ++j) {
          int c = c0 + j;
          st[j] = f2bf(fmaf(xv, pwpb[c], pwpb[64 + c]) + pe[j]);
        }
        *(us8*)(A + swz(r, c0)) = st;
      }
    } else {
      us8 z = {0, 0, 0, 0, 0, 0, 0, 0};
#pragma unroll
      for (int c0 = 0; c0 < 64; c0 += 8) {
        *(us8*)(A + swz(r, c0)) = z;
        *(us8*)(Bq + swz(r, c0)) = z;
      }
    }
  }
  __syncthreads();

  // W <- conv0; wreg <- conv1
  {
    *(float4*)(Wb + swz(tid >> 3, (tid & 7) * 8)) = wreg[0];
    if (tid < 512)
      *(float4*)(Wb + swz((tid >> 3) + 128, (tid & 7) * 8)) = wreg[1];
    wreg[0] = *(const float4*)(wpack + 12288 + (tid >> 3) * 64 + (tid & 7) * 8);
    if (tid < 512)
      wreg[1] = *(const float4*)(wpack + 12288 + ((tid >> 3) + 128) * 64 + (tid & 7) * 8);
  }
  __syncthreads();

  conv_phase<1, false>(A, Bq, Wb, b1 + 0,   wreg, true, wpack + 2 * 12288);
  conv_phase<1, true >(Bq, A, Wb, b2 + 0,   wreg, true, wpack + 3 * 12288);
  conv_phase<2, false>(A, Bq, Wb, b1 + 64,  wreg, true, wpack + 4 * 12288);
  conv_phase<2, true >(Bq, A, Wb, b2 + 64,  wreg, true, wpack + 5 * 12288);
  conv_phase<4, false>(A, Bq, Wb, b1 + 128, wreg, true, wpack + 6 * 12288);
  conv_phase<4, true >(Bq, A, Wb, b2 + 128, wreg, true, wpack + 7 * 12288);
  conv_phase<8, false>(A, Bq, Wb, b1 + 192, wreg, true, (const unsigned short*)nullptr);
  conv_phase<8, true >(Bq, A, Wb, b2 + 192, wreg, false, (const unsigned short*)nullptr);

  // LayerNorm stats per position (channel-permutation-invariant reads)
  if (tid < 512) {
    int r = PADF + tid;
    float s = 0.f, ss = 0.f;
#pragma unroll
    for (int c0 = 0; c0 < 64; c0 += 8) {
      bf16x8 vv = *(const bf16x8*)(A + swz(r, c0));
#pragma unroll
      for (int j = 0; j < 8; ++j) { float v = bf2f((unsigned short)vv[j]); s += v; ss += v * v; }
    }
    float mu = s * 0.015625f;
    float var = fmaxf(ss * 0.015625f - mu * mu, 0.0f);
    mst[tid] = mu;
    mst[512 + tid] = rsqrtf(var + 1e-5f);
  }
  __syncthreads();
  {
    int p = tid & 63, q = tid >> 6;            // 16 groups x 32 rows
    float accp = 0.f;
    int r0 = PADF + q * 32;
    for (int r = r0; r < r0 + 32; ++r)
      accp += (bf2f(A[swz(r, p)]) - mst[r - PADF]) * mst[512 + r - PADF];
    pp[tid] = accp;
  }
  __syncthreads();
  if (tid < 64) {
    float acc = 0.f;
#pragma unroll
    for (int q = 0; q < 16; ++q) acc += pp[q * 64 + tid];
    psum[seq * 64 + tid] = lng[tid] * acc + 512.0f * lnb[tid];
  }
}

// ---------------------------------------------------------------------------
// Kernel 2: transformer + fused MoE gates — 1024 threads, shuffle-LN,
// fused scores+softmax, thin GEMM phases
// ---------------------------------------------------------------------------
__global__ __launch_bounds__(1024, 1) void xf_kernel(
    const float* __restrict__ psum, const float* __restrict__ mask,
    const unsigned short* __restrict__ xfw,
    const float* __restrict__ ppb, const float* __restrict__ pos,
    const float* __restrict__ bq, const float* __restrict__ bk,
    const float* __restrict__ bv, const float* __restrict__ bo,
    const float* __restrict__ l1g, const float* __restrict__ l1b,
    const float* __restrict__ l2g, const float* __restrict__ l2b,
    const float* __restrict__ f1b, const float* __restrict__ f2b,
    const float* __restrict__ og_, const float* __restrict__ ob_,
    const float* __restrict__ gfw, const float* __restrict__ gfb,
    const float* __restrict__ glw, const float* __restrict__ glb,
    const float* __restrict__ grw, const float* __restrict__ grb,
    float* __restrict__ pooledws, float* __restrict__ ctxws,
    float* __restrict__ gwt, int* __restrict__ ecnt, int* __restrict__ elist,
    unsigned short* __restrict__ xbf) {
  extern __shared__ float sm[];
  float* T    = sm;                 // 32*132
  float* QKV  = T + 4224;           // 32*396 (later: gate logits)
  float* S    = QKV + 12672;        // 8448 (probs; later masked ctx)
  float* gv   = S + 8448;           // 512 (mean|max ctx)
  float* mkv  = gv + 512;           // 32 (+32 pad)
  unsigned short* Ybf = (unsigned short*)(mkv + 64);   // [32][136]
  unsigned short* Yb2 = Ybf + 32 * 136;                // [32][136]
  unsigned short* FFH = Yb2 + 32 * 136;                // [32][264]
  const int b = blockIdx.x;
  const int tid = threadIdx.x;
  const int wid = tid >> 6;        // 16 waves
  const int lane = tid & 63;
  const int fr = lane & 15;
  const int g = lane >> 4;
  const int row32 = tid >> 5;
  const int ln32  = tid & 31;

  if (tid < 32) mkv[tid] = mask[b * 32 + tid];
  for (int idx = tid; idx < 2048; idx += 1024) {
    int mm = idx >> 6, p = idx & 63;
    float v = psum[(b * 32 + mm) * 64 + p] * mask[b * 32 + mm] * (1.0f / 512.0f);
    pooledws[(b * 32 + mm) * 64 + p] = v;
    Ybf[mm * 136 + p] = f2bf(v);
  }
  __syncthreads();

  // pool-proj: 16 tiles, 1/wave
  {
    int mt = wid >> 3, nt = wid & 7;
    bf16x8 Af[2];
#pragma unroll
    for (int kf = 0; kf < 2; ++kf)
      Af[kf] = *(const bf16x8*)(Ybf + (mt * 16 + fr) * 136 + kf * 32 + g * 8);
    const unsigned short* bp = xfw + XFW_PPW + (nt * 16 + fr) * 64;
    f32x4 acc = {0.f, 0.f, 0.f, 0.f};
#pragma unroll
    for (int kf = 0; kf < 2; ++kf)
      acc = __builtin_amdgcn_mfma_f32_16x16x32_bf16(Af[kf], *(const bf16x8*)(bp + kf * 32 + g * 8), acc, 0, 0, 0);
    int n = nt * 16 + fr;
    float bb = ppb[n];
#pragma unroll
    for (int j = 0; j < 4; ++j) {
      int m = mt * 16 + g * 4 + j;
      T[m * 132 + n] = acc[j] + bb + pos[m * 128 + n];
    }
  }
  __syncthreads();

#define LN_BF(GAMMA, BETA)                                                     \
  {                                                                            \
    int mm = row32, j0 = ln32 * 4;                                             \
    float4 v4 = *(const float4*)(T + mm * 132 + j0);                           \
    float s = v4.x + v4.y + v4.z + v4.w;                                       \
    float ss = v4.x * v4.x + v4.y * v4.y + v4.z * v4.z + v4.w * v4.w;          \
    _Pragma("unroll") for (int mk = 16; mk >= 1; mk >>= 1) {                   \
      s += __shfl_xor(s, mk); ss += __shfl_xor(ss, mk);                        \
    }                                                                          \
    float mu = s * 0.0078125f;                                                 \
    float rstd = rsqrtf(fmaxf(ss * 0.0078125f - mu * mu, 0.f) + 1e-5f);        \
    us4 st;                                                                    \
    float vv[4] = {v4.x, v4.y, v4.z, v4.w};                                    \
    _Pragma("unroll") for (int j = 0; j < 4; ++j)                              \
      st[j] = f2bf((vv[j] - mu) * rstd * (GAMMA)[j0 + j] + (BETA)[j0 + j]);    \
    *(us4*)(Ybf + mm * 136 + j0) = st;                                         \
  }                                                                            \
  __syncthreads();

  for (int l = 0; l < NL_; ++l) {
    LN_BF(l1g + l * 128, l1b + l * 128)
#pragma unroll
    for (int i = 0; i < 3; ++i) {
      int tt = wid * 3 + i;
      int gem = tt >> 4, r = tt & 15, mt = r >> 3, nt = r & 7;
      const unsigned short* wT = xfw + XFW_QKVO + l * 65536 + gem * 16384;
      const float* bias = (gem == 0) ? bq : (gem == 1) ? bk : bv;
      bf16x8 Afr[4];
#pragma unroll
      for (int kf = 0; kf < 4; ++kf)
        Afr[kf] = *(const bf16x8*)(Ybf + (mt * 16 + fr) * 136 + kf * 32 + g * 8);
      const unsigned short* bp = wT + (nt * 16 + fr) * 128;
      f32x4 acc = {0.f, 0.f, 0.f, 0.f};
#pragma unroll
      for (int kf = 0; kf < 4; ++kf)
        acc = __builtin_amdgcn_mfma_f32_16x16x32_bf16(Afr[kf], *(const bf16x8*)(bp + kf * 32 + g * 8), acc, 0, 0, 0);
      int n = nt * 16 + fr;
      float bb = bias[l * 128 + n];
#pragma unroll
      for (int j = 0; j < 4; ++j)
        QKV[(mt * 16 + g * 4 + j) * 396 + gem * 132 + n] = acc[j] + bb;
    }
    __syncthreads();

    {
      int n = ln32;
      float mbias = (mkv[n] == 0.0f) ? -1e9f : 0.f;
#pragma unroll
      for (int t = 0; t < 8; ++t) {
        int task = row32 * 8 + t;
        int h = task >> 5, mm = task & 31;
        const float* qp = QKV + mm * 396 + h * 16;
        const float* kp = QKV + n * 396 + 132 + h * 16;
        float a = 0;
#pragma unroll
        for (int d = 0; d < 16; ++d) a = fmaf(qp[d], kp[d], a);
        a = a * 0.25f + mbias;
        float mx = a;
#pragma unroll
        for (int mk = 16; mk >= 1; mk >>= 1) mx = fmaxf(mx, __shfl_xor(mx, mk));
        float e = __expf(a - mx);
        float sum = e;
#pragma unroll
        for (int mk = 16; mk >= 1; mk >>= 1) sum += __shfl_xor(sum, mk);
        S[h * 1056 + mm * 33 + n] = e / sum;
      }
    }
    __syncthreads();

    {
      int mm = row32, j0 = ln32 * 4, h = j0 >> 4;
      const float* sp = S + h * 1056 + mm * 33;
      f32x4 a = {0.f, 0.f, 0.f, 0.f};
#pragma unroll 8
      for (int n = 0; n < 32; ++n) {
        float p = sp[n];
        float4 v4 = *(const float4*)(QKV + n * 396 + 264 + j0);
        a[0] = fmaf(p, v4.x, a[0]); a[1] = fmaf(p, v4.y, a[1]);
        a[2] = fmaf(p, v4.z, a[2]); a[3] = fmaf(p, v4.w, a[3]);
      }
      us4 st;
#pragma unroll
      for (int j = 0; j < 4; ++j) st[j] = f2bf(a[j]);
      *(us4*)(Yb2 + mm * 136 + j0) = st;
    }
    __syncthreads();

    {
      int mt = wid >> 3, nt = wid & 7;
      bf16x8 Aw[4];
#pragma unroll
      for (int kf = 0; kf < 4; ++kf)
        Aw[kf] = *(const bf16x8*)(Yb2 + (mt * 16 + fr) * 136 + kf * 32 + g * 8);
      const unsigned short* bp = xfw + XFW_QKVO + l * 65536 + 3 * 16384 + (nt * 16 + fr) * 128;
      f32x4 acc = {0.f, 0.f, 0.f, 0.f};
#pragma unroll
      for (int kf = 0; kf < 4; ++kf)
        acc = __builtin_amdgcn_mfma_f32_16x16x32_bf16(Aw[kf], *(const bf16x8*)(bp + kf * 32 + g * 8), acc, 0, 0, 0);
      int n = nt * 16 + fr;
      float bb = bo[l * 128 + n];
#pragma unroll
      for (int j = 0; j < 4; ++j)
        T[(mt * 16 + g * 4 + j) * 132 + n] += acc[j] + bb;
    }
    __syncthreads();

    LN_BF(l2g + l * 128, l2b + l * 128)
#pragma unroll
    for (int i = 0; i < 2; ++i) {
      int tt = wid * 2 + i;
      int mt = tt >> 4, nt = tt & 15;
      bf16x8 Aff[4];
#pragma unroll
      for (int kf = 0; kf < 4; ++kf)
        Aff[kf] = *(const bf16x8*)(Ybf + (mt * 16 + fr) * 136 + kf * 32 + g * 8);
      const unsigned short* bp = xfw + XFW_F1 + l * 32768 + (nt * 16 + fr) * 128;
      f32x4 acc = {0.f, 0.f, 0.f, 0.f};
#pragma unroll
      for (int kf = 0; kf < 4; ++kf)
        acc = __builtin_amdgcn_mfma_f32_16x16x32_bf16(Aff[kf], *(const bf16x8*)(bp + kf * 32 + g * 8), acc, 0, 0, 0);
      int n = nt * 16 + fr;
      float bb = f1b[l * 256 + n];
#pragma unroll
      for (int j = 0; j < 4; ++j)
        FFH[(mt * 16 + g * 4 + j) * 264 + n] = f2bf(fmaxf(acc[j] + bb, 0.f));
    }
    __syncthreads();
    {
      int mt = wid >> 3, nt = wid & 7;
      bf16x8 Af2[8];
#pragma unroll
      for (int kf = 0; kf < 8; ++kf)
        Af2[kf] = *(const bf16x8*)(FFH + (mt * 16 + fr) * 264 + kf * 32 + g * 8);
      const unsigned short* bp = xfw + XFW_F2 + l * 32768 + (nt * 16 + fr) * 256;
      f32x4 acc = {0.f, 0.f, 0.f, 0.f};
#pragma unroll
      for (int kf = 0; kf < 8; ++kf)
        acc = __builtin_amdgcn_mfma_f32_16x16x32_bf16(Af2[kf], *(const bf16x8*)(bp + kf * 32 + g * 8), acc, 0, 0, 0);
      int n = nt * 16 + fr;
      float bb = f2b[l * 128 + n];
#pragma unroll
      for (int j = 0; j < 4; ++j)
        T[(mt * 16 + g * 4 + j) * 132 + n] += acc[j] + bb;
    }
    __syncthreads();
  }
#undef LN_BF

  {
    int mm = row32, j0 = ln32 * 4;
    float4 v4 = *(const float4*)(T + mm * 132 + j0);
    float s = v4.x + v4.y + v4.z + v4.w;
    float ss = v4.x * v4.x + v4.y * v4.y + v4.z * v4.z + v4.w * v4.w;
#pragma unroll
    for (int mk = 16; mk >= 1; mk >>= 1) { s += __shfl_xor(s, mk); ss += __shfl_xor(ss, mk); }
    float mu = s * 0.0078125f;
    float rstd = rsqrtf(fmaxf(ss * 0.0078125f - mu * mu, 0.f) + 1e-5f);
    float mk_ = mkv[mm];
    float vv[4] = {v4.x, v4.y, v4.z, v4.w};
#pragma unroll
    for (int j = 0; j < 4; ++j) {
      float c = ((vv[j] - mu) * rstd * og_[j0 + j] + ob_[j0 + j]) * mk_;
      S[mm * 132 + j0 + j] = c;
      ctxws[(b * 32 + mm) * 128 + j0 + j] = c;
    }
  }
  __syncthreads();
  if (tid < 128) {
    float cnt = 0;
    for (int mm = 0; mm < 32; ++mm) cnt += mkv[mm];
    cnt = fmaxf(cnt, 1.0f);
    float s = 0, mx = -1e9f;
    for (int mm = 0; mm < 32; ++mm) {
      float v = S[mm * 132 + tid];
      s += v;
      if (mkv[mm] > 0.0f) mx = fmaxf(mx, v);
    }
    gv[tid] = s / cnt;
    gv[128 + tid] = mx;
  }
  __syncthreads();

  float* lg = QKV;  // [34][16]
  if (tid < 544) {
    int lr = tid >> 4, e = tid & 15;
    float a;
    if (lr == 0) {
      a = gfb[e];
      for (int d = 0; d < 256; ++d) a = fmaf(gv[d], gfw[d * 16 + e], a);
    } else if (lr == 1) {
      a = glb[e];
      for (int d = 0; d < 256; ++d) a = fmaf(gv[d], glw[d * 16 + e], a);
    } else {
      int mm = lr - 2;
      a = grb[e];
      for (int d = 0; d < 128; ++d) a = fmaf(S[mm * 132 + d], grw[d * 16 + e], a);
    }
    lg[lr * 16 + e] = a;
  }
  __syncthreads();
  if (tid < 34) {
    const float* lgr = lg + tid * 16;
    int i0 = 0; float v0 = lgr[0];
    for (int e = 1; e < 16; ++e) if (lgr[e] > v0) { v0 = lgr[e]; i0 = e; }
    int i1 = (i0 == 0) ? 1 : 0; float v1 = lgr[i1];
    for (int e = 0; e < 16; ++e) if (e != i0 && lgr[e] > v1) { v1 = lgr[e]; i1 = e; }
    float e1 = __expf(v1 - v0);
    float w0 = 1.0f / (1.0f + e1);
    int gr = (tid == 0) ? b : (tid == 1) ? (16 + b) : (32 + b * 32 + (tid - 2));
    gwt[2 * gr] = w0;  gwt[2 * gr + 1] = 1.0f - w0;
    int p0 = atomicAdd(&ecnt[i0], 1); elist[i0 * 544 + p0] = 2 * gr;
    int p1 = atomicAdd(&ecnt[i1], 1); elist[i1 * 544 + p1] = 2 * gr + 1;
  }
  for (int j = tid; j < 34 * 256; j += 1024) {
    int lr = j >> 8, d = j & 255;
    float v;
    if (lr < 2) v = gv[d];
    else        v = (d < 128) ? S[(lr - 2) * 132 + d] : gv[d - 128];
    int gr = (lr == 0) ? b : (lr == 1) ? (16 + b) : (32 + b * 32 + (lr - 2));
    xbf[gr * 256 + d] = f2bf(v);
  }
}

// ---------------------------------------------------------------------------
// Kernel 4: MoE experts — batched MFMA GEMM per expert
// ---------------------------------------------------------------------------
__global__ __launch_bounds__(512) void moe_kernel(
    const unsigned short* __restrict__ xbf, const float* __restrict__ gwt,
    const int* __restrict__ elist, const int* __restrict__ ecnt,
    const unsigned short* __restrict__ w1t, const float* __restrict__ eb1,
    const unsigned short* __restrict__ w2t, const float* __restrict__ eb2,
    float* __restrict__ yall) {
  __shared__ unsigned short Xb[16 * 264];
  __shared__ unsigned short Hb[16 * 520];
  __shared__ float wl[16];
  __shared__ int rowl[16];
  const int e = blockIdx.x >> 3;
  const int slot = blockIdx.x & 7;
  const int n = ecnt[e];
  const int ntiles = (n + 15) >> 4;
  const int tid = threadIdx.x;
  const int wid = tid >> 6;
  const int lane = tid & 63;
  const int fr = lane & 15;
  const int g = lane >> 4;

  for (int t = slot; t < ntiles; t += 8) {
    if (tid < 16) {
      int idx = t * 16 + tid;
      int id = (idx < n) ? elist[e * 544 + idx] : -1;
      rowl[tid] = (id >= 0) ? (id >> 1) : -1;
      wl[tid] = (id >= 0) ? gwt[id] : 0.f;
    }
    __syncthreads();
    for (int i = tid; i < 512; i += 512) {
      int r = i >> 5, c8 = (i & 31) * 8;
      int row = rowl[r];
      bf16x8 v = {0, 0, 0, 0, 0, 0, 0, 0};
      if (row >= 0) v = *(const bf16x8*)(xbf + row * 256 + c8);
      *(bf16x8*)(Xb + r * 264 + c8) = v;
    }
    __syncthreads();
    bf16x8 Af[8];
#pragma unroll
    for (int kf = 0; kf < 8; ++kf)
      Af[kf] = *(const bf16x8*)(Xb + fr * 264 + kf * 32 + g * 8);
#pragma unroll
    for (int ntl = 0; ntl < 4; ++ntl) {
      int nt = wid * 4 + ntl;
      const unsigned short* bp = w1t + (e * 512 + nt * 16 + fr) * 256;
      f32x4 acc = {0.f, 0.f, 0.f, 0.f};
#pragma unroll
      for (int kf = 0; kf < 8; ++kf)
        acc = __builtin_amdgcn_mfma_f32_16x16x32_bf16(Af[kf], *(const bf16x8*)(bp + kf * 32 + g * 8), acc, 0, 0, 0);
      int h = nt * 16 + fr;
      float b1v = eb1[e * 512 + h];
#pragma unroll
      for (int j = 0; j < 4; ++j)
        Hb[(g * 4 + j) * 520 + h] = f2bf(fmaxf(acc[j] + b1v, 0.f));
    }
    __syncthreads();
    {
      const unsigned short* bp = w2t + (e * 128 + wid * 16 + fr) * 512;
      f32x4 acc = {0.f, 0.f, 0.f, 0.f};
#pragma unroll
      for (int kf = 0; kf < 16; ++kf) {
        bf16x8 Ah = *(const bf16x8*)(Hb + fr * 520 + kf * 32 + g * 8);
        acc = __builtin_amdgcn_mfma_f32_16x16x32_bf16(Ah, *(const bf16x8*)(bp + kf * 32 + g * 8), acc, 0, 0, 0);
      }
      int o = wid * 16 + fr;
      float b2v = eb2[e * 128 + o];
#pragma unroll
      for (int j = 0; j < 4; ++j) {
        int r = g * 4 + j;
        int row = rowl[r];
        if (row >= 0) atomicAdd(&yall[row * 128 + o], wl[r] * (acc[j] + b2v));
      }
    }
    __syncthreads();
  }
}

// ---------------------------------------------------------------------------
// Kernel 5: output heads -> fp32 output
// ---------------------------------------------------------------------------
__global__ __launch_bounds__(192) void heads_kernel(
    const float* __restrict__ x, const float* __restrict__ mask,
    const float* __restrict__ pooledws, const float* __restrict__ ctxws,
    const float* __restrict__ yf, const float* __restrict__ yfail, const float* __restrict__ yrca,
    const float* __restrict__ pw, const float* __restrict__ pb,
    const float* __restrict__ fw, const float* __restrict__ fb,
    const float* __restrict__ rw, const float* __restrict__ rb,
    float* __restrict__ out) {
  __shared__ float yfb[128];
  int b = blockIdx.x, t = threadIdx.x;
  if (t < 128) yfb[t] = yf[b * 128 + t];
  __syncthreads();
  if (t < 96) {
    int mm = t / 3, o = t - mm * 3;
    int s = b * 32 + mm;
    float a = pb[o];
    const float* pl = pooledws + s * 64;
    for (int i = 0; i < 64; ++i) a = fmaf(pl[i], pw[i * 3 + o], a);
    const float* cx = ctxws + s * 128;
    for (int i = 0; i < 128; ++i) a = fmaf(cx[i], pw[(64 + i) * 3 + o], a);
    for (int i = 0; i < 128; ++i) a = fmaf(yfb[i], pw[(192 + i) * 3 + o], a);
    a += x[(b * 512 + 511) * 32 + mm] * mask[b * 32 + mm];
    out[b * 131 + t] = a;
  } else if (t < 99) {
    int o = t - 96;
    float a = fb[o];
    const float* yl = yfail + b * 128;
    for (int i = 0; i < 128; ++i) a = fmaf(yl[i], fw[i * 3 + o], a);
    out[b * 131 + 96 + o] = a;
  } else if (t < 131) {
    int mm = t - 99;
    int s = b * 32 + mm;
    float a = rb[0];
    const float* pl = pooledws + s * 64;
    for (int i = 0; i < 64; ++i) a = fmaf(pl[i], rw[i], a);
    const float* cx = ctxws + s * 128;
    for (int i = 0; i < 128; ++i) a = fmaf(cx[i], rw[64 + i], a);
    const float* yr = yrca + s * 128;
    for (int i = 0; i < 128; ++i) a = fmaf(yr[i], rw[192 + i], a);
    out[b * 131 + 99 + mm] = a;
  }
}

// ---------------------------------------------------------------------------
extern "C" void kernel_launch(void* const* d_in, const int* in_sizes, int n_in,
                              void* d_out, int out_size, void* d_ws, size_t ws_size,
                              hipStream_t stream) {
  (void)in_sizes; (void)n_in; (void)out_size; (void)ws_size;
  const float* x    = (const float*)d_in[0];
  const float* msk  = (const float*)d_in[1];
  const float* epw  = (const float*)d_in[2];
  const float* epb  = (const float*)d_in[3];
  const float* tw1  = (const float*)d_in[4];
  const float* tb1  = (const float*)d_in[5];
  const float* tw2  = (const float*)d_in[6];
  const float* tb2  = (const float*)d_in[7];
  const float* eng  = (const float*)d_in[8];
  const float* enb  = (const float*)d_in[9];
  const float* ppw  = (const float*)d_in[10];
  const float* ppb  = (const float*)d_in[11];
  const float* pos  = (const float*)d_in[12];
  const float* twq  = (const float*)d_in[13];
  const float* tbq  = (const float*)d_in[14];
  const float* twk  = (const float*)d_in[15];
  const float* tbk  = (const float*)d_in[16];
  const float* twv  = (const float*)d_in[17];
  const float* tbv  = (const float*)d_in[18];
  const float* two  = (const float*)d_in[19];
  const float* tbo  = (const float*)d_in[20];
  const float* l1g  = (const float*)d_in[21];
  const float* l1b  = (const float*)d_in[22];
  const float* l2g  = (const float*)d_in[23];
  const float* l2b  = (const float*)d_in[24];
  const float* f1w  = (const float*)d_in[25];
  const float* f1b  = (const float*)d_in[26];
  const float* f2w  = (const float*)d_in[27];
  const float* f2b  = (const float*)d_in[28];
  const float* tog  = (const float*)d_in[29];
  const float* tob  = (const float*)d_in[30];
  const float* ew1  = (const float*)d_in[31];
  const float* eb1  = (const float*)d_in[32];
  const float* ew2  = (const float*)d_in[33];
  const float* eb2  = (const float*)d_in[34];
  const float* gfw  = (const float*)d_in[35];
  const float* gfb  = (const float*)d_in[36];
  const float* glw  = (const float*)d_in[37];
  const float* glb  = (const float*)d_in[38];
  const float* grw  = (const float*)d_in[39];
  const float* grb  = (const float*)d_in[40];
  const float* prw  = (const float*)d_in[41];
  const float* prb  = (const float*)d_in[42];
  const float* fw   = (const float*)d_in[43];
  const float* fb   = (const float*)d_in[44];
  const float* rw   = (const float*)d_in[45];
  const float* rb   = (const float*)d_in[46];

  float* ws      = (float*)d_ws;
  float* psum    = ws;                     // 32768 (of 65536 slot)
  float* pooledw = psum + 65536;           // 32768
  float* ctxw    = pooledw + 32768;        // 65536
  float* yall    = ctxw + 65536;           // 69632
  float* gwt     = yall + 69632;           // 1088
  int*   ecnt    = (int*)(gwt + 1088);     // 16
  int*   elist   = ecnt + 16;              // 8704
  float* peT     = (float*)(elist + 8704); // 32768
  unsigned short* wpack = (unsigned short*)(peT + 32768);  // 98304
  unsigned short* xfw   = wpack + 98304;                   // 270336
  unsigned short* w1t   = xfw + 270336;                    // 2097152
  unsigned short* w2t   = w1t + 2097152;                   // 1048576
  unsigned short* xbf   = w2t + 1048576;                   // 139264

  const int tcn_lds = 2 * ROWSF * LDW * 2 + 192 * LDW * 2 + 128 * 4;  // 160256 B
  const int xf_lds  = (4224 + 12672 + 8448 + 512 + 64) * 4 + (2 * 4352 + 8448) * 2;  // 137824 B
  hipFuncSetAttribute((const void*)tcn_kernel, hipFuncAttributeMaxDynamicSharedMemorySize, tcn_lds);
  hipFuncSetAttribute((const void*)xf_kernel,  hipFuncAttributeMaxDynamicSharedMemorySize, xf_lds);

  prep_kernel<<<911, 256, 0, stream>>>(ppw, twq, twk, twv, two, f1w, f2w, ew1, ew2,
                                       tw1, tw2, xfw, w1t, w2t, wpack, peT, yall, ecnt);
  tcn_kernel<<<512, 1024, tcn_lds, stream>>>(x, msk, epw, epb, wpack, tb1, tb2, peT,
                                             eng, enb, psum);
  xf_kernel<<<16, 1024, xf_lds, stream>>>(psum, msk, xfw, ppb, pos,
                                          tbq, tbk, tbv, tbo,
                                          l1g, l1b, l2g, l2b, f1b, f2b,
                                          tog, tob,
                                          gfw, gfb, glw, glb, grw, grb,
                                          pooledw, ctxw, gwt, ecnt, elist, xbf);
  moe_kernel<<<128, 512, 0, stream>>>(xbf, gwt, elist, ecnt, w1t, eb1, w2t, eb2, yall);
  heads_kernel<<<16, 192, 0, stream>>>(x, msk, pooledw, ctxw,
                                       yall, yall + 2048, yall + 4096,
                                       prw, prb, fw, fb, rw, rb, (float*)d_out);
}

// Round 17
// 244.464 us; speedup vs baseline: 1.0872x; 1.0872x over previous
//
#include <hip/hip_runtime.h>
#include <hip/hip_bf16.h>

// Problem constants
#define B_   16
#define L_   512
#define M_   32
#define P_   64
#define D_   128
#define NH_  8
#define NL_  2
#define E_   16
#define EH_  512
#define O_   128

// TCN: 2 chunks of 256 per sequence, 1024 threads, swizzled LDS
#define CH2   256
#define HALO  60
#define PADF  16
#define ROWS2 336
#define LDW   64

typedef short  bf16x8 __attribute__((ext_vector_type(8)));
typedef float  f32x4  __attribute__((ext_vector_type(4)));
typedef unsigned short us4 __attribute__((ext_vector_type(4)));
typedef unsigned short us8 __attribute__((ext_vector_type(8)));

__device__ __forceinline__ float bf2f(unsigned short h) {
  unsigned u = ((unsigned)h) << 16; float f; __builtin_memcpy(&f, &u, 4); return f;
}
__device__ __forceinline__ unsigned short f2bf(float f) {
  unsigned u; __builtin_memcpy(&u, &f, 4);
  u += 0x7fffu + ((u >> 16) & 1);
  return (unsigned short)(u >> 16);
}
__device__ __forceinline__ int swz(int row, int col_us) {
  return row * LDW + (col_us ^ ((row & 7) << 3));
}

// xfw packed-buffer offsets (bf16 elements)
#define XFW_PPW   0
#define XFW_QKVO  8192
#define XFW_F1    139264
#define XFW_F2    204800

// ---------------------------------------------------------------------------
// Kernel 0: prep — tiled transposes f32->bf16 + conv wpack + PE table
// ---------------------------------------------------------------------------
__global__ __launch_bounds__(256) void prep_kernel(
    const float* __restrict__ ppw,
    const float* __restrict__ twq, const float* __restrict__ twk,
    const float* __restrict__ twv, const float* __restrict__ two,
    const float* __restrict__ f1w, const float* __restrict__ f2w,
    const float* __restrict__ ew1, const float* __restrict__ ew2,
    const float* __restrict__ tw1, const float* __restrict__ tw2,
    unsigned short* __restrict__ xfw, unsigned short* __restrict__ w1t,
    unsigned short* __restrict__ w2t, unsigned short* __restrict__ wpack,
    float* __restrict__ peT) {
  const int b = blockIdx.x;
  const int tid = threadIdx.x;
  if (b < 834) {
    __shared__ float tl[64][65];
    const float* src; unsigned short* dst; int R, C, tr, tc;
    if (b < 2) {
      src = ppw; dst = xfw + XFW_PPW; R = 64; C = 128; tr = 0; tc = b;
    } else if (b < 34) {
      int t = b - 2; int lg = t >> 2; int l = lg >> 2, gem = lg & 3;
      int tt = t & 3; tr = tt >> 1; tc = tt & 1;
      const float* s4 = (gem == 0) ? twq : (gem == 1) ? twk : (gem == 2) ? twv : two;
      src = s4 + l * 16384; dst = xfw + XFW_QKVO + l * 65536 + gem * 16384; R = 128; C = 128;
    } else if (b < 50) {
      int t = b - 34; int l = t >> 3; int tt = t & 7; tr = tt >> 2; tc = tt & 3;
      src = f1w + l * 32768; dst = xfw + XFW_F1 + l * 32768; R = 128; C = 256;
    } else if (b < 66) {
      int t = b - 50; int l = t >> 3; int tt = t & 7; tr = tt >> 1; tc = tt & 1;
      src = f2w + l * 32768; dst = xfw + XFW_F2 + l * 32768; R = 256; C = 128;
    } else if (b < 578) {
      int t = b - 66; int e = t >> 5; int tt = t & 31; tr = tt >> 3; tc = tt & 7;
      src = ew1 + e * 131072; dst = w1t + e * 131072; R = 256; C = 512;
    } else {
      int t = b - 578; int e = t >> 4; int tt = t & 15; tr = tt >> 1; tc = tt & 1;
      src = ew2 + e * 65536; dst = w2t + e * 65536; R = 512; C = 128;
    }
    for (int i = tid; i < 4096; i += 256) {
      int r = i >> 6, c = i & 63;
      tl[r][c] = src[(tr * 64 + r) * C + tc * 64 + c];
    }
    __syncthreads();
    for (int i = tid; i < 4096; i += 256) {
      int c = i >> 6, r = i & 63;
      dst[(tc * 64 + c) * R + tr * 64 + r] = f2bf(tl[r][c]);
    }
  } else if (b < 840) {
    int base = (b - 834) * 16384;
    for (int q = tid; q < 16384; q += 256) {
      int i = base + q;
      int c = i & 63, o = (i >> 6) & 63, tlc = i >> 12;
      int t = tlc % 3, lc = tlc / 3, lvl = lc >> 1;
      const float* src = (lc & 1) ? tw2 : tw1;
      wpack[i] = f2bf(src[lvl * 12288 + o * 192 + c * 3 + t]);
    }
  } else {
    int base = (b - 840) * 16384;
    for (int q = tid; q < 16384; q += 256) {
      int j = base + q; int ll = j >> 6, c = j & 63;
      float dv = expf(-0.14391157f * (float)(c & ~1));
      float ang = (float)ll * dv;
      peT[j] = (c & 1) ? cosf(ang) : sinf(ang);
    }
  }
}

// ---------------------------------------------------------------------------
// Kernel 1: TCN — chunk-256, 1024 threads (16 waves), W dbuf, 1 barrier/conv
// WLOAD at phase start (hides under conv); WSTORE at phase end.
// ---------------------------------------------------------------------------
template <int DIL, bool RES>
__device__ __forceinline__ void conv_mfma(const unsigned short* __restrict__ IN,
                                          unsigned short* __restrict__ OUT,
                                          const unsigned short* __restrict__ Wt,
                                          const float* __restrict__ bias, bool zh) {
  const int tid  = threadIdx.x;
  const int wid  = tid >> 6;        // 16 waves
  const int lane = tid & 63;
  const int fr   = lane & 15;
  const int g    = lane >> 4;
  const int ot0  = (wid & 1) * 2;   // 2 o-tiles per wave
  const int ng   = wid >> 1;        // 8 n-groups; nt = ng + 8k, k<3, nt<20

  bf16x8 Af[2][6];
#pragma unroll
  for (int oo = 0; oo < 2; ++oo)
#pragma unroll
    for (int t = 0; t < 3; ++t)
#pragma unroll
      for (int kh = 0; kh < 2; ++kh) {
        int wr = t * 64 + (ot0 + oo) * 16 + fr;
        Af[oo][t * 2 + kh] = *(const bf16x8*)(Wt + swz(wr, kh * 32 + g * 8));
      }
  float bv[2][4];
#pragma unroll
  for (int oo = 0; oo < 2; ++oo)
#pragma unroll
    for (int j = 0; j < 4; ++j) bv[oo][j] = bias[(ot0 + oo) * 16 + g * 4 + j];

#pragma unroll
  for (int k = 0; k < 3; ++k) {
    const int nt = ng + k * 8;
    if (nt < 20) {
      const int rb = PADF + nt * 16 + fr;
      bf16x8 Bf[6];
#pragma unroll
      for (int t = 0; t < 3; ++t) {
        int r = rb + (t - 2) * DIL;   // causal taps at l-2d, l-d, l
#pragma unroll
        for (int kh = 0; kh < 2; ++kh)
          Bf[t * 2 + kh] = *(const bf16x8*)(IN + swz(r, kh * 32 + g * 8));
      }
      f32x4 acc[2];
#pragma unroll
      for (int oo = 0; oo < 2; ++oo) {
        f32x4 a; a[0] = bv[oo][0]; a[1] = bv[oo][1]; a[2] = bv[oo][2]; a[3] = bv[oo][3];
        acc[oo] = a;
      }
#pragma unroll
      for (int f = 0; f < 6; ++f)
#pragma unroll
        for (int oo = 0; oo < 2; ++oo)
          acc[oo] = __builtin_amdgcn_mfma_f32_16x16x32_bf16(Af[oo][f], Bf[f], acc[oo], 0, 0, 0);

      const float zm = (zh && rb < PADF + HALO) ? 0.f : 1.f;
#pragma unroll
      for (int oo = 0; oo < 2; ++oo) {
        unsigned short* op = OUT + swz(rb, (ot0 + oo) * 16 + g * 4);
        us4 old;
        if (RES) old = *(const us4*)op;
        us4 st;
#pragma unroll
        for (int j = 0; j < 4; ++j) {
          float v = fmaxf(acc[oo][j], 0.f);
          if (RES) v = fmaxf(v + bf2f(old[j]), 0.f);
          st[j] = f2bf(v * zm);
        }
        *(us4*)op = st;
      }
    }
  }
}

__global__ __launch_bounds__(1024) void tcn_kernel(
    const float* __restrict__ x, const float* __restrict__ mask,
    const float* __restrict__ pw, const float* __restrict__ pb,
    const unsigned short* __restrict__ wpack,
    const float* __restrict__ b1, const float* __restrict__ b2,
    const float* __restrict__ peT,
    const float* __restrict__ lng, const float* __restrict__ lnb,
    float* __restrict__ psum2) {
  extern __shared__ unsigned short smu[];
  unsigned short* A  = smu;
  unsigned short* Bq = A + ROWS2 * LDW;
  unsigned short* W0 = Bq + ROWS2 * LDW;
  unsigned short* W1 = W0 + 192 * LDW;
  float* fbase = (float*)(W1 + 192 * LDW);
  float* xr   = fbase;
  float* pwpb = fbase + 336;
  float* mst  = fbase;
  float* pp   = fbase + 512;

  const int bx = blockIdx.x;
  const int seq = bx & 511;
  const int chunk = bx >> 9;
  const int b = seq >> 5;
  const int m = seq & 31;
  if (mask[b * M_ + m] == 0.0f) return;
  const int tid = threadIdx.x;
  const bool zh = (chunk == 0);
  const int lbase = chunk * CH2 - HALO;

  float4 wreg[2];
#define WLOAD(li)                                                               \
  { wreg[0] = *(const float4*)(wpack + (li) * 12288 + (tid >> 3) * 64 + (tid & 7) * 8); \
    if (tid < 512)                                                              \
      wreg[1] = *(const float4*)(wpack + (li) * 12288 + ((tid >> 3) + 128) * 64 + (tid & 7) * 8); }
#define WSTORE(buf)                                                             \
  { *(float4*)((buf) + swz(tid >> 3, (tid & 7) * 8)) = wreg[0];                 \
    if (tid < 512)                                                              \
      *(float4*)((buf) + swz((tid >> 3) + 128, (tid & 7) * 8)) = wreg[1]; }

  WLOAD(0);
  if (tid < 64)       pwpb[tid] = pw[tid];
  else if (tid < 128) pwpb[tid] = pb[tid - 64];
  if (tid < ROWS2) {
    int w = tid - PADF, l = lbase + w;
    float xv = 0.f;
    if (w >= 0 && w < CH2 + HALO && l >= 0 && l < L_) xv = x[(b * L_ + l) * M_ + m];
    xr[tid] = xv;
  }
  __syncthreads();

  // build A = proj(x) + PE (bf16, swizzled); invalid rows zeroed
  for (int idx = tid; idx < ROWS2 * 8; idx += 1024) {
    int r = idx >> 3, c0 = (idx & 7) * 8;
    int w = r - PADF, l = lbase + w;
    us8 st;
    if (w >= 0 && w < CH2 + HALO && l >= 0 && l < L_) {
      float xv = xr[r];
      const float4* pe4 = (const float4*)(peT + l * 64 + c0);
      float4 pa = pe4[0], pc = pe4[1];
      float pe[8] = {pa.x, pa.y, pa.z, pa.w, pc.x, pc.y, pc.z, pc.w};
#pragma unroll
      for (int j = 0; j < 8; ++j) {
        int c = c0 + j;
        st[j] = f2bf(fmaf(xv, pwpb[c], pwpb[64 + c]) + pe[j]);
      }
    } else {
#pragma unroll
      for (int j = 0; j < 8; ++j) st[j] = 0;
    }
    *(us8*)(A + swz(r, c0)) = st;
  }
  for (int idx = tid; idx < PADF * LDW; idx += 1024) Bq[idx] = 0;
  WSTORE(W0);
  __syncthreads();

  // phase i: WLOAD(i+1) at start (hides under conv), WSTORE at end, 1 barrier
  WLOAD(1);
  conv_mfma<1, false>(A, Bq, W0, b1 + 0,   zh); WSTORE(W1); __syncthreads();
  WLOAD(2);
  conv_mfma<1, true >(Bq, A, W1, b2 + 0,   zh); WSTORE(W0); __syncthreads();
  WLOAD(3);
  conv_mfma<2, false>(A, Bq, W0, b1 + 64,  zh); WSTORE(W1); __syncthreads();
  WLOAD(4);
  conv_mfma<2, true >(Bq, A, W1, b2 + 64,  zh); WSTORE(W0); __syncthreads();
  WLOAD(5);
  conv_mfma<4, false>(A, Bq, W0, b1 + 128, zh); WSTORE(W1); __syncthreads();
  WLOAD(6);
  conv_mfma<4, true >(Bq, A, W1, b2 + 128, zh); WSTORE(W0); __syncthreads();
  WLOAD(7);
  conv_mfma<8, false>(A, Bq, W0, b1 + 192, zh); WSTORE(W1); __syncthreads();
  conv_mfma<8, true >(Bq, A, W1, b2 + 192, zh);             __syncthreads();
#undef WLOAD
#undef WSTORE

  // LayerNorm stats at each of 256 valid positions (permutation-invariant reads)
  if (tid < CH2) {
    int r = PADF + HALO + tid;
    float s = 0.f, ss = 0.f;
#pragma unroll
    for (int c0 = 0; c0 < 64; c0 += 8) {
      bf16x8 vv = *(const bf16x8*)(A + swz(r, c0));
#pragma unroll
      for (int j = 0; j < 8; ++j) { float v = bf2f((unsigned short)vv[j]); s += v; ss += v * v; }
    }
    float mu = s * 0.015625f;
    float var = fmaxf(ss * 0.015625f - mu * mu, 0.0f);
    mst[tid] = mu;
    mst[CH2 + tid] = rsqrtf(var + 1e-5f);
  }
  __syncthreads();
  {
    int p = tid & 63, q = tid >> 6;            // 16 groups x 16 rows
    float accp = 0.f;
    int r0 = PADF + HALO + q * 16;
    for (int r = r0; r < r0 + 16; ++r)
      accp += (bf2f(A[swz(r, p)]) - mst[r - PADF - HALO]) * mst[CH2 + r - PADF - HALO];
    pp[tid] = accp;
  }
  __syncthreads();
  if (tid < 64) {
    float acc = 0.f;
#pragma unroll
    for (int q = 0; q < 16; ++q) acc += pp[q * 64 + tid];
    psum2[chunk * 32768 + seq * 64 + tid] = lng[tid] * acc + 256.0f * lnb[tid];
  }
}

// ---------------------------------------------------------------------------
// Kernel 2: transformer + fused MoE gates — 1024 threads, shuffle-LN,
// fused scores+softmax, thin GEMM phases
// ---------------------------------------------------------------------------
__global__ __launch_bounds__(1024) void xf_kernel(
    const float* __restrict__ psum2, const float* __restrict__ mask,
    const unsigned short* __restrict__ xfw,
    const float* __restrict__ ppb, const float* __restrict__ pos,
    const float* __restrict__ bq, const float* __restrict__ bk,
    const float* __restrict__ bv, const float* __restrict__ bo,
    const float* __restrict__ l1g, const float* __restrict__ l1b,
    const float* __restrict__ l2g, const float* __restrict__ l2b,
    const float* __restrict__ f1b, const float* __restrict__ f2b,
    const float* __restrict__ og_, const float* __restrict__ ob_,
    const float* __restrict__ gfw, const float* __restrict__ gfb,
    const float* __restrict__ glw, const float* __restrict__ glb,
    const float* __restrict__ grw, const float* __restrict__ grb,
    float* __restrict__ pooledws, float* __restrict__ ctxws,
    float* __restrict__ gwt, int* __restrict__ ecnt, int* __restrict__ elist,
    unsigned short* __restrict__ xbf) {
  extern __shared__ float sm[];
  float* T    = sm;                 // 32*132
  float* QKV  = T + 4224;           // 32*396 (later: gate logits)
  float* S    = QKV + 12672;        // 8448 (probs; later masked ctx)
  float* gv   = S + 8448;           // 512 (mean|max ctx)
  float* mkv  = gv + 512;           // 32 (+32 pad)
  unsigned short* Ybf = (unsigned short*)(mkv + 64);   // [32][136]
  unsigned short* Yb2 = Ybf + 32 * 136;                // [32][136]
  unsigned short* FFH = Yb2 + 32 * 136;                // [32][264]
  const int b = blockIdx.x;
  const int tid = threadIdx.x;
  const int wid = tid >> 6;        // 16 waves
  const int lane = tid & 63;
  const int fr = lane & 15;
  const int g = lane >> 4;
  const int row32 = tid >> 5;
  const int ln32  = tid & 31;

  if (tid < 32) mkv[tid] = mask[b * 32 + tid];
  for (int idx = tid; idx < 2048; idx += 1024) {
    int mm = idx >> 6, p = idx & 63;
    const float* p4 = psum2 + (b * 32 + mm) * 64 + p;
    float v = (p4[0] + p4[32768]) * mask[b * 32 + mm] * (1.0f / 512.0f);
    pooledws[(b * 32 + mm) * 64 + p] = v;
    Ybf[mm * 136 + p] = f2bf(v);
  }
  __syncthreads();

  // pool-proj: 16 tiles, 1/wave
  {
    int mt = wid >> 3, nt = wid & 7;
    bf16x8 Af[2];
#pragma unroll
    for (int kf = 0; kf < 2; ++kf)
      Af[kf] = *(const bf16x8*)(Ybf + (mt * 16 + fr) * 136 + kf * 32 + g * 8);
    const unsigned short* bp = xfw + XFW_PPW + (nt * 16 + fr) * 64;
    f32x4 acc = {0.f, 0.f, 0.f, 0.f};
#pragma unroll
    for (int kf = 0; kf < 2; ++kf)
      acc = __builtin_amdgcn_mfma_f32_16x16x32_bf16(Af[kf], *(const bf16x8*)(bp + kf * 32 + g * 8), acc, 0, 0, 0);
    int n = nt * 16 + fr;
    float bb = ppb[n];
#pragma unroll
    for (int j = 0; j < 4; ++j) {
      int m = mt * 16 + g * 4 + j;
      T[m * 132 + n] = acc[j] + bb + pos[m * 128 + n];
    }
  }
  __syncthreads();

#define LN_BF(GAMMA, BETA)                                                     \
  {                                                                            \
    int mm = row32, j0 = ln32 * 4;                                             \
    float4 v4 = *(const float4*)(T + mm * 132 + j0);                           \
    float s = v4.x + v4.y + v4.z + v4.w;                                       \
    float ss = v4.x * v4.x + v4.y * v4.y + v4.z * v4.z + v4.w * v4.w;          \
    _Pragma("unroll") for (int mk = 16; mk >= 1; mk >>= 1) {                   \
      s += __shfl_xor(s, mk); ss += __shfl_xor(ss, mk);                        \
    }                                                                          \
    float mu = s * 0.0078125f;                                                 \
    float rstd = rsqrtf(fmaxf(ss * 0.0078125f - mu * mu, 0.f) + 1e-5f);        \
    us4 st;                                                                    \
    float vv[4] = {v4.x, v4.y, v4.z, v4.w};                                    \
    _Pragma("unroll") for (int j = 0; j < 4; ++j)                              \
      st[j] = f2bf((vv[j] - mu) * rstd * (GAMMA)[j0 + j] + (BETA)[j0 + j]);    \
    *(us4*)(Ybf + mm * 136 + j0) = st;                                         \
  }                                                                            \
  __syncthreads();

  for (int l = 0; l < NL_; ++l) {
    LN_BF(l1g + l * 128, l1b + l * 128)
#pragma unroll
    for (int i = 0; i < 3; ++i) {
      int tt = wid * 3 + i;
      int gem = tt >> 4, r = tt & 15, mt = r >> 3, nt = r & 7;
      const unsigned short* wT = xfw + XFW_QKVO + l * 65536 + gem * 16384;
      const float* bias = (gem == 0) ? bq : (gem == 1) ? bk : bv;
      bf16x8 Afr[4];
#pragma unroll
      for (int kf = 0; kf < 4; ++kf)
        Afr[kf] = *(const bf16x8*)(Ybf + (mt * 16 + fr) * 136 + kf * 32 + g * 8);
      const unsigned short* bp = wT + (nt * 16 + fr) * 128;
      f32x4 acc = {0.f, 0.f, 0.f, 0.f};
#pragma unroll
      for (int kf = 0; kf < 4; ++kf)
        acc = __builtin_amdgcn_mfma_f32_16x16x32_bf16(Afr[kf], *(const bf16x8*)(bp + kf * 32 + g * 8), acc, 0, 0, 0);
      int n = nt * 16 + fr;
      float bb = bias[l * 128 + n];
#pragma unroll
      for (int j = 0; j < 4; ++j)
        QKV[(mt * 16 + g * 4 + j) * 396 + gem * 132 + n] = acc[j] + bb;
    }
    __syncthreads();

    {
      int n = ln32;
      float mbias = (mkv[n] == 0.0f) ? -1e9f : 0.f;
#pragma unroll
      for (int t = 0; t < 8; ++t) {
        int task = row32 * 8 + t;
        int h = task >> 5, mm = task & 31;
        const float* qp = QKV + mm * 396 + h * 16;
        const float* kp = QKV + n * 396 + 132 + h * 16;
        float a = 0;
#pragma unroll
        for (int d = 0; d < 16; ++d) a = fmaf(qp[d], kp[d], a);
        a = a * 0.25f + mbias;
        float mx = a;
#pragma unroll
        for (int mk = 16; mk >= 1; mk >>= 1) mx = fmaxf(mx, __shfl_xor(mx, mk));
        float e = __expf(a - mx);
        float sum = e;
#pragma unroll
        for (int mk = 16; mk >= 1; mk >>= 1) sum += __shfl_xor(sum, mk);
        S[h * 1056 + mm * 33 + n] = e / sum;
      }
    }
    __syncthreads();

    {
      int mm = row32, j0 = ln32 * 4, h = j0 >> 4;
      const float* sp = S + h * 1056 + mm * 33;
      f32x4 a = {0.f, 0.f, 0.f, 0.f};
#pragma unroll 8
      for (int n = 0; n < 32; ++n) {
        float p = sp[n];
        float4 v4 = *(const float4*)(QKV + n * 396 + 264 + j0);
        a[0] = fmaf(p, v4.x, a[0]); a[1] = fmaf(p, v4.y, a[1]);
        a[2] = fmaf(p, v4.z, a[2]); a[3] = fmaf(p, v4.w, a[3]);
      }
      us4 st;
#pragma unroll
      for (int j = 0; j < 4; ++j) st[j] = f2bf(a[j]);
      *(us4*)(Yb2 + mm * 136 + j0) = st;
    }
    __syncthreads();

    {
      int mt = wid >> 3, nt = wid & 7;
      bf16x8 Aw[4];
#pragma unroll
      for (int kf = 0; kf < 4; ++kf)
        Aw[kf] = *(const bf16x8*)(Yb2 + (mt * 16 + fr) * 136 + kf * 32 + g * 8);
      const unsigned short* bp = xfw + XFW_QKVO + l * 65536 + 3 * 16384 + (nt * 16 + fr) * 128;
      f32x4 acc = {0.f, 0.f, 0.f, 0.f};
#pragma unroll
      for (int kf = 0; kf < 4; ++kf)
        acc = __builtin_amdgcn_mfma_f32_16x16x32_bf16(Aw[kf], *(const bf16x8*)(bp + kf * 32 + g * 8), acc, 0, 0, 0);
      int n = nt * 16 + fr;
      float bb = bo[l * 128 + n];
#pragma unroll
      for (int j = 0; j < 4; ++j)
        T[(mt * 16 + g * 4 + j) * 132 + n] += acc[j] + bb;
    }
    __syncthreads();

    LN_BF(l2g + l * 128, l2b + l * 128)
#pragma unroll
    for (int i = 0; i < 2; ++i) {
      int tt = wid * 2 + i;
      int mt = tt >> 4, nt = tt & 15;
      bf16x8 Aff[4];
#pragma unroll
      for (int kf = 0; kf < 4; ++kf)
        Aff[kf] = *(const bf16x8*)(Ybf + (mt * 16 + fr) * 136 + kf * 32 + g * 8);
      const unsigned short* bp = xfw + XFW_F1 + l * 32768 + (nt * 16 + fr) * 128;
      f32x4 acc = {0.f, 0.f, 0.f, 0.f};
#pragma unroll
      for (int kf = 0; kf < 4; ++kf)
        acc = __builtin_amdgcn_mfma_f32_16x16x32_bf16(Aff[kf], *(const bf16x8*)(bp + kf * 32 + g * 8), acc, 0, 0, 0);
      int n = nt * 16 + fr;
      float bb = f1b[l * 256 + n];
#pragma unroll
      for (int j = 0; j < 4; ++j)
        FFH[(mt * 16 + g * 4 + j) * 264 + n] = f2bf(fmaxf(acc[j] + bb, 0.f));
    }
    __syncthreads();
    {
      int mt = wid >> 3, nt = wid & 7;
      bf16x8 Af2[8];
#pragma unroll
      for (int kf = 0; kf < 8; ++kf)
        Af2[kf] = *(const bf16x8*)(FFH + (mt * 16 + fr) * 264 + kf * 32 + g * 8);
      const unsigned short* bp = xfw + XFW_F2 + l * 32768 + (nt * 16 + fr) * 256;
      f32x4 acc = {0.f, 0.f, 0.f, 0.f};
#pragma unroll
      for (int kf = 0; kf < 8; ++kf)
        acc = __builtin_amdgcn_mfma_f32_16x16x32_bf16(Af2[kf], *(const bf16x8*)(bp + kf * 32 + g * 8), acc, 0, 0, 0);
      int n = nt * 16 + fr;
      float bb = f2b[l * 128 + n];
#pragma unroll
      for (int j = 0; j < 4; ++j)
        T[(mt * 16 + g * 4 + j) * 132 + n] += acc[j] + bb;
    }
    __syncthreads();
  }
#undef LN_BF

  {
    int mm = row32, j0 = ln32 * 4;
    float4 v4 = *(const float4*)(T + mm * 132 + j0);
    float s = v4.x + v4.y + v4.z + v4.w;
    float ss = v4.x * v4.x + v4.y * v4.y + v4.z * v4.z + v4.w * v4.w;
#pragma unroll
    for (int mk = 16; mk >= 1; mk >>= 1) { s += __shfl_xor(s, mk); ss += __shfl_xor(ss, mk); }
    float mu = s * 0.0078125f;
    float rstd = rsqrtf(fmaxf(ss * 0.0078125f - mu * mu, 0.f) + 1e-5f);
    float mk_ = mkv[mm];
    float vv[4] = {v4.x, v4.y, v4.z, v4.w};
#pragma unroll
    for (int j = 0; j < 4; ++j) {
      float c = ((vv[j] - mu) * rstd * og_[j0 + j] + ob_[j0 + j]) * mk_;
      S[mm * 132 + j0 + j] = c;
      ctxws[(b * 32 + mm) * 128 + j0 + j] = c;
    }
  }
  __syncthreads();
  if (tid < 128) {
    float cnt = 0;
    for (int mm = 0; mm < 32; ++mm) cnt += mkv[mm];
    cnt = fmaxf(cnt, 1.0f);
    float s = 0, mx = -1e9f;
    for (int mm = 0; mm < 32; ++mm) {
      float v = S[mm * 132 + tid];
      s += v;
      if (mkv[mm] > 0.0f) mx = fmaxf(mx, v);
    }
    gv[tid] = s / cnt;
    gv[128 + tid] = mx;
  }
  __syncthreads();

  float* lg = QKV;  // [34][16]
  if (tid < 544) {
    int lr = tid >> 4, e = tid & 15;
    float a;
    if (lr == 0) {
      a = gfb[e];
      for (int d = 0; d < 256; ++d) a = fmaf(gv[d], gfw[d * 16 + e], a);
    } else if (lr == 1) {
      a = glb[e];
      for (int d = 0; d < 256; ++d) a = fmaf(gv[d], glw[d * 16 + e], a);
    } else {
      int mm = lr - 2;
      a = grb[e];
      for (int d = 0; d < 128; ++d) a = fmaf(S[mm * 132 + d], grw[d * 16 + e], a);
    }
    lg[lr * 16 + e] = a;
  }
  __syncthreads();
  if (tid < 34) {
    const float* lgr = lg + tid * 16;
    int i0 = 0; float v0 = lgr[0];
    for (int e = 1; e < 16; ++e) if (lgr[e] > v0) { v0 = lgr[e]; i0 = e; }
    int i1 = (i0 == 0) ? 1 : 0; float v1 = lgr[i1];
    for (int e = 0; e < 16; ++e) if (e != i0 && lgr[e] > v1) { v1 = lgr[e]; i1 = e; }
    float e1 = __expf(v1 - v0);
    float w0 = 1.0f / (1.0f + e1);
    int gr = (tid == 0) ? b : (tid == 1) ? (16 + b) : (32 + b * 32 + (tid - 2));
    gwt[2 * gr] = w0;  gwt[2 * gr + 1] = 1.0f - w0;
    int p0 = atomicAdd(&ecnt[i0], 1); elist[i0 * 544 + p0] = 2 * gr;
    int p1 = atomicAdd(&ecnt[i1], 1); elist[i1 * 544 + p1] = 2 * gr + 1;
  }
  for (int j = tid; j < 34 * 256; j += 1024) {
    int lr = j >> 8, d = j & 255;
    float v;
    if (lr < 2) v = gv[d];
    else        v = (d < 128) ? S[(lr - 2) * 132 + d] : gv[d - 128];
    int gr = (lr == 0) ? b : (lr == 1) ? (16 + b) : (32 + b * 32 + (lr - 2));
    xbf[gr * 256 + d] = f2bf(v);
  }
}

// ---------------------------------------------------------------------------
// Kernel 4: MoE experts — batched MFMA GEMM per expert
// ---------------------------------------------------------------------------
__global__ __launch_bounds__(512) void moe_kernel(
    const unsigned short* __restrict__ xbf, const float* __restrict__ gwt,
    const int* __restrict__ elist, const int* __restrict__ ecnt,
    const unsigned short* __restrict__ w1t, const float* __restrict__ eb1,
    const unsigned short* __restrict__ w2t, const float* __restrict__ eb2,
    float* __restrict__ yall) {
  __shared__ unsigned short Xb[16 * 264];
  __shared__ unsigned short Hb[16 * 520];
  __shared__ float wl[16];
  __shared__ int rowl[16];
  const int e = blockIdx.x >> 3;
  const int slot = blockIdx.x & 7;
  const int n = ecnt[e];
  const int ntiles = (n + 15) >> 4;
  const int tid = threadIdx.x;
  const int wid = tid >> 6;
  const int lane = tid & 63;
  const int fr = lane & 15;
  const int g = lane >> 4;

  for (int t = slot; t < ntiles; t += 8) {
    if (tid < 16) {
      int idx = t * 16 + tid;
      int id = (idx < n) ? elist[e * 544 + idx] : -1;
      rowl[tid] = (id >= 0) ? (id >> 1) : -1;
      wl[tid] = (id >= 0) ? gwt[id] : 0.f;
    }
    __syncthreads();
    for (int i = tid; i < 512; i += 512) {
      int r = i >> 5, c8 = (i & 31) * 8;
      int row = rowl[r];
      bf16x8 v = {0, 0, 0, 0, 0, 0, 0, 0};
      if (row >= 0) v = *(const bf16x8*)(xbf + row * 256 + c8);
      *(bf16x8*)(Xb + r * 264 + c8) = v;
    }
    __syncthreads();
    bf16x8 Af[8];
#pragma unroll
    for (int kf = 0; kf < 8; ++kf)
      Af[kf] = *(const bf16x8*)(Xb + fr * 264 + kf * 32 + g * 8);
#pragma unroll
    for (int ntl = 0; ntl < 4; ++ntl) {
      int nt = wid * 4 + ntl;
      const unsigned short* bp = w1t + (e * 512 + nt * 16 + fr) * 256;
      f32x4 acc = {0.f, 0.f, 0.f, 0.f};
#pragma unroll
      for (int kf = 0; kf < 8; ++kf)
        acc = __builtin_amdgcn_mfma_f32_16x16x32_bf16(Af[kf], *(const bf16x8*)(bp + kf * 32 + g * 8), acc, 0, 0, 0);
      int h = nt * 16 + fr;
      float b1v = eb1[e * 512 + h];
#pragma unroll
      for (int j = 0; j < 4; ++j)
        Hb[(g * 4 + j) * 520 + h] = f2bf(fmaxf(acc[j] + b1v, 0.f));
    }
    __syncthreads();
    {
      const unsigned short* bp = w2t + (e * 128 + wid * 16 + fr) * 512;
      f32x4 acc = {0.f, 0.f, 0.f, 0.f};
#pragma unroll
      for (int kf = 0; kf < 16; ++kf) {
        bf16x8 Ah = *(const bf16x8*)(Hb + fr * 520 + kf * 32 + g * 8);
        acc = __builtin_amdgcn_mfma_f32_16x16x32_bf16(Ah, *(const bf16x8*)(bp + kf * 32 + g * 8), acc, 0, 0, 0);
      }
      int o = wid * 16 + fr;
      float b2v = eb2[e * 128 + o];
#pragma unroll
      for (int j = 0; j < 4; ++j) {
        int r = g * 4 + j;
        int row = rowl[r];
        if (row >= 0) atomicAdd(&yall[row * 128 + o], wl[r] * (acc[j] + b2v));
      }
    }
    __syncthreads();
  }
}

// ---------------------------------------------------------------------------
// Kernel 5: output heads -> fp32 output
// ---------------------------------------------------------------------------
__global__ __launch_bounds__(192) void heads_kernel(
    const float* __restrict__ x, const float* __restrict__ mask,
    const float* __restrict__ pooledws, const float* __restrict__ ctxws,
    const float* __restrict__ yf, const float* __restrict__ yfail, const float* __restrict__ yrca,
    const float* __restrict__ pw, const float* __restrict__ pb,
    const float* __restrict__ fw, const float* __restrict__ fb,
    const float* __restrict__ rw, const float* __restrict__ rb,
    float* __restrict__ out) {
  __shared__ float yfb[128];
  int b = blockIdx.x, t = threadIdx.x;
  if (t < 128) yfb[t] = yf[b * 128 + t];
  __syncthreads();
  if (t < 96) {
    int mm = t / 3, o = t - mm * 3;
    int s = b * 32 + mm;
    float a = pb[o];
    const float* pl = pooledws + s * 64;
    for (int i = 0; i < 64; ++i) a = fmaf(pl[i], pw[i * 3 + o], a);
    const float* cx = ctxws + s * 128;
    for (int i = 0; i < 128; ++i) a = fmaf(cx[i], pw[(64 + i) * 3 + o], a);
    for (int i = 0; i < 128; ++i) a = fmaf(yfb[i], pw[(192 + i) * 3 + o], a);
    a += x[(b * 512 + 511) * 32 + mm] * mask[b * 32 + mm];
    out[b * 131 + t] = a;
  } else if (t < 99) {
    int o = t - 96;
    float a = fb[o];
    const float* yl = yfail + b * 128;
    for (int i = 0; i < 128; ++i) a = fmaf(yl[i], fw[i * 3 + o], a);
    out[b * 131 + 96 + o] = a;
  } else if (t < 131) {
    int mm = t - 99;
    int s = b * 32 + mm;
    float a = rb[0];
    const float* pl = pooledws + s * 64;
    for (int i = 0; i < 64; ++i) a = fmaf(pl[i], rw[i], a);
    const float* cx = ctxws + s * 128;
    for (int i = 0; i < 128; ++i) a = fmaf(cx[i], rw[64 + i], a);
    const float* yr = yrca + s * 128;
    for (int i = 0; i < 128; ++i) a = fmaf(yr[i], rw[192 + i], a);
    out[b * 131 + 99 + mm] = a;
  }
}

// ---------------------------------------------------------------------------
extern "C" void kernel_launch(void* const* d_in, const int* in_sizes, int n_in,
                              void* d_out, int out_size, void* d_ws, size_t ws_size,
                              hipStream_t stream) {
  (void)in_sizes; (void)n_in; (void)out_size; (void)ws_size;
  const float* x    = (const float*)d_in[0];
  const float* msk  = (const float*)d_in[1];
  const float* epw  = (const float*)d_in[2];
  const float* epb  = (const float*)d_in[3];
  const float* tw1  = (const float*)d_in[4];
  const float* tb1  = (const float*)d_in[5];
  const float* tw2  = (const float*)d_in[6];
  const float* tb2  = (const float*)d_in[7];
  const float* eng  = (const float*)d_in[8];
  const float* enb  = (const float*)d_in[9];
  const float* ppw  = (const float*)d_in[10];
  const float* ppb  = (const float*)d_in[11];
  const float* pos  = (const float*)d_in[12];
  const float* twq  = (const float*)d_in[13];
  const float* tbq  = (const float*)d_in[14];
  const float* twk  = (const float*)d_in[15];
  const float* tbk  = (const float*)d_in[16];
  const float* twv  = (const float*)d_in[17];
  const float* tbv  = (const float*)d_in[18];
  const float* two  = (const float*)d_in[19];
  const float* tbo  = (const float*)d_in[20];
  const float* l1g  = (const float*)d_in[21];
  const float* l1b  = (const float*)d_in[22];
  const float* l2g  = (const float*)d_in[23];
  const float* l2b  = (const float*)d_in[24];
  const float* f1w  = (const float*)d_in[25];
  const float* f1b  = (const float*)d_in[26];
  const float* f2w  = (const float*)d_in[27];
  const float* f2b  = (const float*)d_in[28];
  const float* tog  = (const float*)d_in[29];
  const float* tob  = (const float*)d_in[30];
  const float* ew1  = (const float*)d_in[31];
  const float* eb1  = (const float*)d_in[32];
  const float* ew2  = (const float*)d_in[33];
  const float* eb2  = (const float*)d_in[34];
  const float* gfw  = (const float*)d_in[35];
  const float* gfb  = (const float*)d_in[36];
  const float* glw  = (const float*)d_in[37];
  const float* glb  = (const float*)d_in[38];
  const float* grw  = (const float*)d_in[39];
  const float* grb  = (const float*)d_in[40];
  const float* prw  = (const float*)d_in[41];
  const float* prb  = (const float*)d_in[42];
  const float* fw   = (const float*)d_in[43];
  const float* fb   = (const float*)d_in[44];
  const float* rw   = (const float*)d_in[45];
  const float* rb   = (const float*)d_in[46];

  float* ws      = (float*)d_ws;
  float* psum2   = ws;                     // 65536
  float* pooledw = psum2 + 65536;          // 32768
  float* ctxw    = pooledw + 32768;        // 65536
  float* yall    = ctxw + 65536;           // 69632
  float* gwt     = yall + 69632;           // 1088
  int*   ecnt    = (int*)(gwt + 1088);     // 16
  int*   elist   = ecnt + 16;              // 8704
  float* peT     = (float*)(elist + 8704); // 32768
  unsigned short* wpack = (unsigned short*)(peT + 32768);  // 98304
  unsigned short* xfw   = wpack + 98304;                   // 270336
  unsigned short* w1t   = xfw + 270336;                    // 2097152
  unsigned short* w2t   = w1t + 2097152;                   // 1048576
  unsigned short* xbf   = w2t + 1048576;                   // 139264

  const int tcn_lds = (2 * ROWS2 * LDW + 2 * 192 * LDW) * 2 + 1536 * 4;  // 141312 B
  const int xf_lds  = (4224 + 12672 + 8448 + 512 + 64) * 4 + (2 * 4352 + 8448) * 2;  // 137824 B
  hipFuncSetAttribute((const void*)tcn_kernel, hipFuncAttributeMaxDynamicSharedMemorySize, tcn_lds);
  hipFuncSetAttribute((const void*)xf_kernel,  hipFuncAttributeMaxDynamicSharedMemorySize, xf_lds);

  hipMemsetAsync(yall, 0, 69632 * sizeof(float), stream);
  hipMemsetAsync(ecnt, 0, 16 * sizeof(int), stream);

  prep_kernel<<<842, 256, 0, stream>>>(ppw, twq, twk, twv, two, f1w, f2w, ew1, ew2,
                                       tw1, tw2, xfw, w1t, w2t, wpack, peT);
  tcn_kernel<<<1024, 1024, tcn_lds, stream>>>(x, msk, epw, epb, wpack, tb1, tb2, peT,
                                              eng, enb, psum2);
  xf_kernel<<<16, 1024, xf_lds, stream>>>(psum2, msk, xfw, ppb, pos,
                                          tbq, tbk, tbv, tbo,
                                          l1g, l1b, l2g, l2b, f1b, f2b,
                                          tog, tob,
                                          gfw, gfb, glw, glb, grw, grb,
                                          pooledw, ctxw, gwt, ecnt, elist, xbf);
  moe_kernel<<<128, 512, 0, stream>>>(xbf, gwt, elist, ecnt, w1t, eb1, w2t, eb2, yall);
  heads_kernel<<<16, 192, 0, stream>>>(x, msk, pooledw, ctxw,
                                       yall, yall + 2048, yall + 4096,
                                       prw, prb, fw, fb, rw, rb, (float*)d_out);
}

// Round 18
// 237.735 us; speedup vs baseline: 1.1180x; 1.0283x over previous
//
#include <hip/hip_runtime.h>
#include <hip/hip_bf16.h>

// Problem constants
#define B_   16
#define L_   512
#define M_   32
#define P_   64
#define D_   128
#define NH_  8
#define NL_  2
#define E_   16
#define EH_  512
#define O_   128

// TCN: 2 chunks of 256 per sequence, 1024 threads, swizzled LDS
#define CH2   256
#define HALO  60
#define PADF  16
#define ROWS2 336
#define LDW   64

typedef short  bf16x8 __attribute__((ext_vector_type(8)));
typedef float  f32x4  __attribute__((ext_vector_type(4)));
typedef unsigned short us4 __attribute__((ext_vector_type(4)));
typedef unsigned short us8 __attribute__((ext_vector_type(8)));

__device__ __forceinline__ float bf2f(unsigned short h) {
  unsigned u = ((unsigned)h) << 16; float f; __builtin_memcpy(&f, &u, 4); return f;
}
__device__ __forceinline__ unsigned short f2bf(float f) {
  unsigned u; __builtin_memcpy(&u, &f, 4);
  u += 0x7fffu + ((u >> 16) & 1);
  return (unsigned short)(u >> 16);
}
__device__ __forceinline__ int swz(int row, int col_us) {
  return row * LDW + (col_us ^ ((row & 7) << 3));
}

// xfw packed-buffer offsets (bf16 elements)
#define XFW_PPW   0
#define XFW_QKVO  8192
#define XFW_F1    139264
#define XFW_F2    204800

// ---------------------------------------------------------------------------
// Kernel 0: prep — transposes f32->bf16 + conv wpack + PE table + zero yall/ecnt
// ---------------------------------------------------------------------------
__global__ __launch_bounds__(256) void prep_kernel(
    const float* __restrict__ ppw,
    const float* __restrict__ twq, const float* __restrict__ twk,
    const float* __restrict__ twv, const float* __restrict__ two,
    const float* __restrict__ f1w, const float* __restrict__ f2w,
    const float* __restrict__ ew1, const float* __restrict__ ew2,
    const float* __restrict__ tw1, const float* __restrict__ tw2,
    unsigned short* __restrict__ xfw, unsigned short* __restrict__ w1t,
    unsigned short* __restrict__ w2t, unsigned short* __restrict__ wpack,
    float* __restrict__ peT, float* __restrict__ yall, int* __restrict__ ecnt) {
  const int b = blockIdx.x;
  const int tid = threadIdx.x;
  if (b < 834) {
    __shared__ float tl[64][65];
    const float* src; unsigned short* dst; int R, C, tr, tc;
    if (b < 2) {
      src = ppw; dst = xfw + XFW_PPW; R = 64; C = 128; tr = 0; tc = b;
    } else if (b < 34) {
      int t = b - 2; int lg = t >> 2; int l = lg >> 2, gem = lg & 3;
      int tt = t & 3; tr = tt >> 1; tc = tt & 1;
      const float* s4 = (gem == 0) ? twq : (gem == 1) ? twk : (gem == 2) ? twv : two;
      src = s4 + l * 16384; dst = xfw + XFW_QKVO + l * 65536 + gem * 16384; R = 128; C = 128;
    } else if (b < 50) {
      int t = b - 34; int l = t >> 3; int tt = t & 7; tr = tt >> 2; tc = tt & 3;
      src = f1w + l * 32768; dst = xfw + XFW_F1 + l * 32768; R = 128; C = 256;
    } else if (b < 66) {
      int t = b - 50; int l = t >> 3; int tt = t & 7; tr = tt >> 1; tc = tt & 1;
      src = f2w + l * 32768; dst = xfw + XFW_F2 + l * 32768; R = 256; C = 128;
    } else if (b < 578) {
      int t = b - 66; int e = t >> 5; int tt = t & 31; tr = tt >> 3; tc = tt & 7;
      src = ew1 + e * 131072; dst = w1t + e * 131072; R = 256; C = 512;
    } else {
      int t = b - 578; int e = t >> 4; int tt = t & 15; tr = tt >> 1; tc = tt & 1;
      src = ew2 + e * 65536; dst = w2t + e * 65536; R = 512; C = 128;
    }
    for (int i = tid; i < 4096; i += 256) {
      int r = i >> 6, c = i & 63;
      tl[r][c] = src[(tr * 64 + r) * C + tc * 64 + c];
    }
    __syncthreads();
    for (int i = tid; i < 4096; i += 256) {
      int c = i >> 6, r = i & 63;
      dst[(tc * 64 + c) * R + tr * 64 + r] = f2bf(tl[r][c]);
    }
  } else if (b < 840) {
    int base = (b - 834) * 16384;
    for (int q = tid; q < 16384; q += 256) {
      int i = base + q;
      int c = i & 63, o = (i >> 6) & 63, tlc = i >> 12;
      int t = tlc % 3, lc = tlc / 3, lvl = lc >> 1;
      const float* src = (lc & 1) ? tw2 : tw1;
      wpack[i] = f2bf(src[lvl * 12288 + o * 192 + c * 3 + t]);
    }
  } else if (b < 842) {
    int base = (b - 840) * 16384;
    for (int q = tid; q < 16384; q += 256) {
      int j = base + q; int ll = j >> 6, c = j & 63;
      float dv = expf(-0.14391157f * (float)(c & ~1));
      float ang = (float)ll * dv;
      peT[j] = (c & 1) ? cosf(ang) : sinf(ang);
    }
  } else {
    int j = b - 842;
    if (j < 68) {
      for (int q = tid; q < 1024; q += 256) yall[j * 1024 + q] = 0.f;
    } else {
      if (tid < 16) ecnt[tid] = 0;
    }
  }
}

// ---------------------------------------------------------------------------
// Kernel 1: TCN — chunk-256, 1024 threads (16 waves), W dbuf, 1 barrier/conv
// WLOAD at phase start (hides under conv); WSTORE at phase end.
// ---------------------------------------------------------------------------
template <int DIL, bool RES>
__device__ __forceinline__ void conv_mfma(const unsigned short* __restrict__ IN,
                                          unsigned short* __restrict__ OUT,
                                          const unsigned short* __restrict__ Wt,
                                          const float* __restrict__ bias, bool zh) {
  const int tid  = threadIdx.x;
  const int wid  = tid >> 6;        // 16 waves
  const int lane = tid & 63;
  const int fr   = lane & 15;
  const int g    = lane >> 4;
  const int ot0  = (wid & 1) * 2;   // 2 o-tiles per wave
  const int ng   = wid >> 1;        // 8 n-groups; nt = ng + 8k, k<3, nt<20

  bf16x8 Af[2][6];
#pragma unroll
  for (int oo = 0; oo < 2; ++oo)
#pragma unroll
    for (int t = 0; t < 3; ++t)
#pragma unroll
      for (int kh = 0; kh < 2; ++kh) {
        int wr = t * 64 + (ot0 + oo) * 16 + fr;
        Af[oo][t * 2 + kh] = *(const bf16x8*)(Wt + swz(wr, kh * 32 + g * 8));
      }
  float bv[2][4];
#pragma unroll
  for (int oo = 0; oo < 2; ++oo)
#pragma unroll
    for (int j = 0; j < 4; ++j) bv[oo][j] = bias[(ot0 + oo) * 16 + g * 4 + j];

#pragma unroll
  for (int k = 0; k < 3; ++k) {
    const int nt = ng + k * 8;
    if (nt < 20) {
      const int rb = PADF + nt * 16 + fr;
      bf16x8 Bf[6];
#pragma unroll
      for (int t = 0; t < 3; ++t) {
        int r = rb + (t - 2) * DIL;   // causal taps at l-2d, l-d, l
#pragma unroll
        for (int kh = 0; kh < 2; ++kh)
          Bf[t * 2 + kh] = *(const bf16x8*)(IN + swz(r, kh * 32 + g * 8));
      }
      f32x4 acc[2];
#pragma unroll
      for (int oo = 0; oo < 2; ++oo) {
        f32x4 a; a[0] = bv[oo][0]; a[1] = bv[oo][1]; a[2] = bv[oo][2]; a[3] = bv[oo][3];
        acc[oo] = a;
      }
#pragma unroll
      for (int f = 0; f < 6; ++f)
#pragma unroll
        for (int oo = 0; oo < 2; ++oo)
          acc[oo] = __builtin_amdgcn_mfma_f32_16x16x32_bf16(Af[oo][f], Bf[f], acc[oo], 0, 0, 0);

      const float zm = (zh && rb < PADF + HALO) ? 0.f : 1.f;
#pragma unroll
      for (int oo = 0; oo < 2; ++oo) {
        unsigned short* op = OUT + swz(rb, (ot0 + oo) * 16 + g * 4);
        us4 old;
        if (RES) old = *(const us4*)op;
        us4 st;
#pragma unroll
        for (int j = 0; j < 4; ++j) {
          float v = fmaxf(acc[oo][j], 0.f);
          if (RES) v = fmaxf(v + bf2f(old[j]), 0.f);
          st[j] = f2bf(v * zm);
        }
        *(us4*)op = st;
      }
    }
  }
}

__global__ __launch_bounds__(1024) void tcn_kernel(
    const float* __restrict__ x, const float* __restrict__ mask,
    const float* __restrict__ pw, const float* __restrict__ pb,
    const unsigned short* __restrict__ wpack,
    const float* __restrict__ b1, const float* __restrict__ b2,
    const float* __restrict__ peT,
    const float* __restrict__ lng, const float* __restrict__ lnb,
    float* __restrict__ psum2) {
  extern __shared__ unsigned short smu[];
  unsigned short* A  = smu;
  unsigned short* Bq = A + ROWS2 * LDW;
  unsigned short* W0 = Bq + ROWS2 * LDW;
  unsigned short* W1 = W0 + 192 * LDW;
  float* fbase = (float*)(W1 + 192 * LDW);
  float* xr   = fbase;
  float* pwpb = fbase + 336;
  float* mst  = fbase;
  float* pp   = fbase + 512;

  const int bx = blockIdx.x;
  const int seq = bx & 511;
  const int chunk = bx >> 9;
  const int b = seq >> 5;
  const int m = seq & 31;
  if (mask[b * M_ + m] == 0.0f) return;
  const int tid = threadIdx.x;
  const bool zh = (chunk == 0);
  const int lbase = chunk * CH2 - HALO;

  float4 wreg[2];
#define WLOAD(li)                                                               \
  { wreg[0] = *(const float4*)(wpack + (li) * 12288 + (tid >> 3) * 64 + (tid & 7) * 8); \
    if (tid < 512)                                                              \
      wreg[1] = *(const float4*)(wpack + (li) * 12288 + ((tid >> 3) + 128) * 64 + (tid & 7) * 8); }
#define WSTORE(buf)                                                             \
  { *(float4*)((buf) + swz(tid >> 3, (tid & 7) * 8)) = wreg[0];                 \
    if (tid < 512)                                                              \
      *(float4*)((buf) + swz((tid >> 3) + 128, (tid & 7) * 8)) = wreg[1]; }

  WLOAD(0);
  if (tid < 64)       pwpb[tid] = pw[tid];
  else if (tid < 128) pwpb[tid] = pb[tid - 64];
  if (tid < ROWS2) {
    int w = tid - PADF, l = lbase + w;
    float xv = 0.f;
    if (w >= 0 && w < CH2 + HALO && l >= 0 && l < L_) xv = x[(b * L_ + l) * M_ + m];
    xr[tid] = xv;
  }
  __syncthreads();

  // build A = proj(x) + PE (bf16, swizzled); invalid rows zeroed
  for (int idx = tid; idx < ROWS2 * 8; idx += 1024) {
    int r = idx >> 3, c0 = (idx & 7) * 8;
    int w = r - PADF, l = lbase + w;
    us8 st;
    if (w >= 0 && w < CH2 + HALO && l >= 0 && l < L_) {
      float xv = xr[r];
      const float4* pe4 = (const float4*)(peT + l * 64 + c0);
      float4 pa = pe4[0], pc = pe4[1];
      float pe[8] = {pa.x, pa.y, pa.z, pa.w, pc.x, pc.y, pc.z, pc.w};
#pragma unroll
      for (int j = 0; j < 8; ++j) {
        int c = c0 + j;
        st[j] = f2bf(fmaf(xv, pwpb[c], pwpb[64 + c]) + pe[j]);
      }
    } else {
#pragma unroll
      for (int j = 0; j < 8; ++j) st[j] = 0;
    }
    *(us8*)(A + swz(r, c0)) = st;
  }
  for (int idx = tid; idx < PADF * LDW; idx += 1024) Bq[idx] = 0;
  WSTORE(W0);
  __syncthreads();

  // phase i: WLOAD(i+1) at start (hides under conv), WSTORE at end, 1 barrier
  WLOAD(1);
  conv_mfma<1, false>(A, Bq, W0, b1 + 0,   zh); WSTORE(W1); __syncthreads();
  WLOAD(2);
  conv_mfma<1, true >(Bq, A, W1, b2 + 0,   zh); WSTORE(W0); __syncthreads();
  WLOAD(3);
  conv_mfma<2, false>(A, Bq, W0, b1 + 64,  zh); WSTORE(W1); __syncthreads();
  WLOAD(4);
  conv_mfma<2, true >(Bq, A, W1, b2 + 64,  zh); WSTORE(W0); __syncthreads();
  WLOAD(5);
  conv_mfma<4, false>(A, Bq, W0, b1 + 128, zh); WSTORE(W1); __syncthreads();
  WLOAD(6);
  conv_mfma<4, true >(Bq, A, W1, b2 + 128, zh); WSTORE(W0); __syncthreads();
  WLOAD(7);
  conv_mfma<8, false>(A, Bq, W0, b1 + 192, zh); WSTORE(W1); __syncthreads();
  conv_mfma<8, true >(Bq, A, W1, b2 + 192, zh);             __syncthreads();
#undef WLOAD
#undef WSTORE

  // LayerNorm stats at each of 256 valid positions (permutation-invariant reads)
  if (tid < CH2) {
    int r = PADF + HALO + tid;
    float s = 0.f, ss = 0.f;
#pragma unroll
    for (int c0 = 0; c0 < 64; c0 += 8) {
      bf16x8 vv = *(const bf16x8*)(A + swz(r, c0));
#pragma unroll
      for (int j = 0; j < 8; ++j) { float v = bf2f((unsigned short)vv[j]); s += v; ss += v * v; }
    }
    float mu = s * 0.015625f;
    float var = fmaxf(ss * 0.015625f - mu * mu, 0.0f);
    mst[tid] = mu;
    mst[CH2 + tid] = rsqrtf(var + 1e-5f);
  }
  __syncthreads();
  {
    int p = tid & 63, q = tid >> 6;            // 16 groups x 16 rows
    float accp = 0.f;
    int r0 = PADF + HALO + q * 16;
    for (int r = r0; r < r0 + 16; ++r)
      accp += (bf2f(A[swz(r, p)]) - mst[r - PADF - HALO]) * mst[CH2 + r - PADF - HALO];
    pp[tid] = accp;
  }
  __syncthreads();
  if (tid < 64) {
    float acc = 0.f;
#pragma unroll
    for (int q = 0; q < 16; ++q) acc += pp[q * 64 + tid];
    psum2[chunk * 32768 + seq * 64 + tid] = lng[tid] * acc + 256.0f * lnb[tid];
  }
}

// ---------------------------------------------------------------------------
// Kernel 2: transformer + fused MoE gates — 1024 threads, shuffle-LN,
// fused scores+softmax, thin GEMM phases
// ---------------------------------------------------------------------------
__global__ __launch_bounds__(1024) void xf_kernel(
    const float* __restrict__ psum2, const float* __restrict__ mask,
    const unsigned short* __restrict__ xfw,
    const float* __restrict__ ppb, const float* __restrict__ pos,
    const float* __restrict__ bq, const float* __restrict__ bk,
    const float* __restrict__ bv, const float* __restrict__ bo,
    const float* __restrict__ l1g, const float* __restrict__ l1b,
    const float* __restrict__ l2g, const float* __restrict__ l2b,
    const float* __restrict__ f1b, const float* __restrict__ f2b,
    const float* __restrict__ og_, const float* __restrict__ ob_,
    const float* __restrict__ gfw, const float* __restrict__ gfb,
    const float* __restrict__ glw, const float* __restrict__ glb,
    const float* __restrict__ grw, const float* __restrict__ grb,
    float* __restrict__ pooledws, float* __restrict__ ctxws,
    float* __restrict__ gwt, int* __restrict__ ecnt, int* __restrict__ elist,
    unsigned short* __restrict__ xbf) {
  extern __shared__ float sm[];
  float* T    = sm;                 // 32*132
  float* QKV  = T + 4224;           // 32*396 (later: gate logits)
  float* S    = QKV + 12672;        // 8448 (probs; later masked ctx)
  float* gv   = S + 8448;           // 512 (mean|max ctx)
  float* mkv  = gv + 512;           // 32 (+32 pad)
  unsigned short* Ybf = (unsigned short*)(mkv + 64);   // [32][136]
  unsigned short* Yb2 = Ybf + 32 * 136;                // [32][136]
  unsigned short* FFH = Yb2 + 32 * 136;                // [32][264]
  const int b = blockIdx.x;
  const int tid = threadIdx.x;
  const int wid = tid >> 6;        // 16 waves
  const int lane = tid & 63;
  const int fr = lane & 15;
  const int g = lane >> 4;
  const int row32 = tid >> 5;
  const int ln32  = tid & 31;

  if (tid < 32) mkv[tid] = mask[b * 32 + tid];
  for (int idx = tid; idx < 2048; idx += 1024) {
    int mm = idx >> 6, p = idx & 63;
    const float* p4 = psum2 + (b * 32 + mm) * 64 + p;
    float v = (p4[0] + p4[32768]) * mask[b * 32 + mm] * (1.0f / 512.0f);
    pooledws[(b * 32 + mm) * 64 + p] = v;
    Ybf[mm * 136 + p] = f2bf(v);
  }
  __syncthreads();

  // pool-proj: 16 tiles, 1/wave
  {
    int mt = wid >> 3, nt = wid & 7;
    bf16x8 Af[2];
#pragma unroll
    for (int kf = 0; kf < 2; ++kf)
      Af[kf] = *(const bf16x8*)(Ybf + (mt * 16 + fr) * 136 + kf * 32 + g * 8);
    const unsigned short* bp = xfw + XFW_PPW + (nt * 16 + fr) * 64;
    f32x4 acc = {0.f, 0.f, 0.f, 0.f};
#pragma unroll
    for (int kf = 0; kf < 2; ++kf)
      acc = __builtin_amdgcn_mfma_f32_16x16x32_bf16(Af[kf], *(const bf16x8*)(bp + kf * 32 + g * 8), acc, 0, 0, 0);
    int n = nt * 16 + fr;
    float bb = ppb[n];
#pragma unroll
    for (int j = 0; j < 4; ++j) {
      int m = mt * 16 + g * 4 + j;
      T[m * 132 + n] = acc[j] + bb + pos[m * 128 + n];
    }
  }
  __syncthreads();

#define LN_BF(GAMMA, BETA)                                                     \
  {                                                                            \
    int mm = row32, j0 = ln32 * 4;                                             \
    float4 v4 = *(const float4*)(T + mm * 132 + j0);                           \
    float s = v4.x + v4.y + v4.z + v4.w;                                       \
    float ss = v4.x * v4.x + v4.y * v4.y + v4.z * v4.z + v4.w * v4.w;          \
    _Pragma("unroll") for (int mk = 16; mk >= 1; mk >>= 1) {                   \
      s += __shfl_xor(s, mk); ss += __shfl_xor(ss, mk);                        \
    }                                                                          \
    float mu = s * 0.0078125f;                                                 \
    float rstd = rsqrtf(fmaxf(ss * 0.0078125f - mu * mu, 0.f) + 1e-5f);        \
    us4 st;                                                                    \
    float vv[4] = {v4.x, v4.y, v4.z, v4.w};                                    \
    _Pragma("unroll") for (int j = 0; j < 4; ++j)                              \
      st[j] = f2bf((vv[j] - mu) * rstd * (GAMMA)[j0 + j] + (BETA)[j0 + j]);    \
    *(us4*)(Ybf + mm * 136 + j0) = st;                                         \
  }                                                                            \
  __syncthreads();

  for (int l = 0; l < NL_; ++l) {
    LN_BF(l1g + l * 128, l1b + l * 128)
#pragma unroll
    for (int i = 0; i < 3; ++i) {
      int tt = wid * 3 + i;
      int gem = tt >> 4, r = tt & 15, mt = r >> 3, nt = r & 7;
      const unsigned short* wT = xfw + XFW_QKVO + l * 65536 + gem * 16384;
      const float* bias = (gem == 0) ? bq : (gem == 1) ? bk : bv;
      bf16x8 Afr[4];
#pragma unroll
      for (int kf = 0; kf < 4; ++kf)
        Afr[kf] = *(const bf16x8*)(Ybf + (mt * 16 + fr) * 136 + kf * 32 + g * 8);
      const unsigned short* bp = wT + (nt * 16 + fr) * 128;
      f32x4 acc = {0.f, 0.f, 0.f, 0.f};
#pragma unroll
      for (int kf = 0; kf < 4; ++kf)
        acc = __builtin_amdgcn_mfma_f32_16x16x32_bf16(Afr[kf], *(const bf16x8*)(bp + kf * 32 + g * 8), acc, 0, 0, 0);
      int n = nt * 16 + fr;
      float bb = bias[l * 128 + n];
#pragma unroll
      for (int j = 0; j < 4; ++j)
        QKV[(mt * 16 + g * 4 + j) * 396 + gem * 132 + n] = acc[j] + bb;
    }
    __syncthreads();

    {
      int n = ln32;
      float mbias = (mkv[n] == 0.0f) ? -1e9f : 0.f;
#pragma unroll
      for (int t = 0; t < 8; ++t) {
        int task = row32 * 8 + t;
        int h = task >> 5, mm = task & 31;
        const float* qp = QKV + mm * 396 + h * 16;
        const float* kp = QKV + n * 396 + 132 + h * 16;
        float a = 0;
#pragma unroll
        for (int d = 0; d < 16; ++d) a = fmaf(qp[d], kp[d], a);
        a = a * 0.25f + mbias;
        float mx = a;
#pragma unroll
        for (int mk = 16; mk >= 1; mk >>= 1) mx = fmaxf(mx, __shfl_xor(mx, mk));
        float e = __expf(a - mx);
        float sum = e;
#pragma unroll
        for (int mk = 16; mk >= 1; mk >>= 1) sum += __shfl_xor(sum, mk);
        S[h * 1056 + mm * 33 + n] = e / sum;
      }
    }
    __syncthreads();

    {
      int mm = row32, j0 = ln32 * 4, h = j0 >> 4;
      const float* sp = S + h * 1056 + mm * 33;
      f32x4 a = {0.f, 0.f, 0.f, 0.f};
#pragma unroll 8
      for (int n = 0; n < 32; ++n) {
        float p = sp[n];
        float4 v4 = *(const float4*)(QKV + n * 396 + 264 + j0);
        a[0] = fmaf(p, v4.x, a[0]); a[1] = fmaf(p, v4.y, a[1]);
        a[2] = fmaf(p, v4.z, a[2]); a[3] = fmaf(p, v4.w, a[3]);
      }
      us4 st;
#pragma unroll
      for (int j = 0; j < 4; ++j) st[j] = f2bf(a[j]);
      *(us4*)(Yb2 + mm * 136 + j0) = st;
    }
    __syncthreads();

    {
      int mt = wid >> 3, nt = wid & 7;
      bf16x8 Aw[4];
#pragma unroll
      for (int kf = 0; kf < 4; ++kf)
        Aw[kf] = *(const bf16x8*)(Yb2 + (mt * 16 + fr) * 136 + kf * 32 + g * 8);
      const unsigned short* bp = xfw + XFW_QKVO + l * 65536 + 3 * 16384 + (nt * 16 + fr) * 128;
      f32x4 acc = {0.f, 0.f, 0.f, 0.f};
#pragma unroll
      for (int kf = 0; kf < 4; ++kf)
        acc = __builtin_amdgcn_mfma_f32_16x16x32_bf16(Aw[kf], *(const bf16x8*)(bp + kf * 32 + g * 8), acc, 0, 0, 0);
      int n = nt * 16 + fr;
      float bb = bo[l * 128 + n];
#pragma unroll
      for (int j = 0; j < 4; ++j)
        T[(mt * 16 + g * 4 + j) * 132 + n] += acc[j] + bb;
    }
    __syncthreads();

    LN_BF(l2g + l * 128, l2b + l * 128)
#pragma unroll
    for (int i = 0; i < 2; ++i) {
      int tt = wid * 2 + i;
      int mt = tt >> 4, nt = tt & 15;
      bf16x8 Aff[4];
#pragma unroll
      for (int kf = 0; kf < 4; ++kf)
        Aff[kf] = *(const bf16x8*)(Ybf + (mt * 16 + fr) * 136 + kf * 32 + g * 8);
      const unsigned short* bp = xfw + XFW_F1 + l * 32768 + (nt * 16 + fr) * 128;
      f32x4 acc = {0.f, 0.f, 0.f, 0.f};
#pragma unroll
      for (int kf = 0; kf < 4; ++kf)
        acc = __builtin_amdgcn_mfma_f32_16x16x32_bf16(Aff[kf], *(const bf16x8*)(bp + kf * 32 + g * 8), acc, 0, 0, 0);
      int n = nt * 16 + fr;
      float bb = f1b[l * 256 + n];
#pragma unroll
      for (int j = 0; j < 4; ++j)
        FFH[(mt * 16 + g * 4 + j) * 264 + n] = f2bf(fmaxf(acc[j] + bb, 0.f));
    }
    __syncthreads();
    {
      int mt = wid >> 3, nt = wid & 7;
      bf16x8 Af2[8];
#pragma unroll
      for (int kf = 0; kf < 8; ++kf)
        Af2[kf] = *(const bf16x8*)(FFH + (mt * 16 + fr) * 264 + kf * 32 + g * 8);
      const unsigned short* bp = xfw + XFW_F2 + l * 32768 + (nt * 16 + fr) * 256;
      f32x4 acc = {0.f, 0.f, 0.f, 0.f};
#pragma unroll
      for (int kf = 0; kf < 8; ++kf)
        acc = __builtin_amdgcn_mfma_f32_16x16x32_bf16(Af2[kf], *(const bf16x8*)(bp + kf * 32 + g * 8), acc, 0, 0, 0);
      int n = nt * 16 + fr;
      float bb = f2b[l * 128 + n];
#pragma unroll
      for (int j = 0; j < 4; ++j)
        T[(mt * 16 + g * 4 + j) * 132 + n] += acc[j] + bb;
    }
    __syncthreads();
  }
#undef LN_BF

  {
    int mm = row32, j0 = ln32 * 4;
    float4 v4 = *(const float4*)(T + mm * 132 + j0);
    float s = v4.x + v4.y + v4.z + v4.w;
    float ss = v4.x * v4.x + v4.y * v4.y + v4.z * v4.z + v4.w * v4.w;
#pragma unroll
    for (int mk = 16; mk >= 1; mk >>= 1) { s += __shfl_xor(s, mk); ss += __shfl_xor(ss, mk); }
    float mu = s * 0.0078125f;
    float rstd = rsqrtf(fmaxf(ss * 0.0078125f - mu * mu, 0.f) + 1e-5f);
    float mk_ = mkv[mm];
    float vv[4] = {v4.x, v4.y, v4.z, v4.w};
#pragma unroll
    for (int j = 0; j < 4; ++j) {
      float c = ((vv[j] - mu) * rstd * og_[j0 + j] + ob_[j0 + j]) * mk_;
      S[mm * 132 + j0 + j] = c;
      ctxws[(b * 32 + mm) * 128 + j0 + j] = c;
    }
  }
  __syncthreads();
  if (tid < 128) {
    float cnt = 0;
    for (int mm = 0; mm < 32; ++mm) cnt += mkv[mm];
    cnt = fmaxf(cnt, 1.0f);
    float s = 0, mx = -1e9f;
    for (int mm = 0; mm < 32; ++mm) {
      float v = S[mm * 132 + tid];
      s += v;
      if (mkv[mm] > 0.0f) mx = fmaxf(mx, v);
    }
    gv[tid] = s / cnt;
    gv[128 + tid] = mx;
  }
  __syncthreads();

  float* lg = QKV;  // [34][16]
  if (tid < 544) {
    int lr = tid >> 4, e = tid & 15;
    float a;
    if (lr == 0) {
      a = gfb[e];
      for (int d = 0; d < 256; ++d) a = fmaf(gv[d], gfw[d * 16 + e], a);
    } else if (lr == 1) {
      a = glb[e];
      for (int d = 0; d < 256; ++d) a = fmaf(gv[d], glw[d * 16 + e], a);
    } else {
      int mm = lr - 2;
      a = grb[e];
      for (int d = 0; d < 128; ++d) a = fmaf(S[mm * 132 + d], grw[d * 16 + e], a);
    }
    lg[lr * 16 + e] = a;
  }
  __syncthreads();
  if (tid < 34) {
    const float* lgr = lg + tid * 16;
    int i0 = 0; float v0 = lgr[0];
    for (int e = 1; e < 16; ++e) if (lgr[e] > v0) { v0 = lgr[e]; i0 = e; }
    int i1 = (i0 == 0) ? 1 : 0; float v1 = lgr[i1];
    for (int e = 0; e < 16; ++e) if (e != i0 && lgr[e] > v1) { v1 = lgr[e]; i1 = e; }
    float e1 = __expf(v1 - v0);
    float w0 = 1.0f / (1.0f + e1);
    int gr = (tid == 0) ? b : (tid == 1) ? (16 + b) : (32 + b * 32 + (tid - 2));
    gwt[2 * gr] = w0;  gwt[2 * gr + 1] = 1.0f - w0;
    int p0 = atomicAdd(&ecnt[i0], 1); elist[i0 * 544 + p0] = 2 * gr;
    int p1 = atomicAdd(&ecnt[i1], 1); elist[i1 * 544 + p1] = 2 * gr + 1;
  }
  for (int j = tid; j < 34 * 256; j += 1024) {
    int lr = j >> 8, d = j & 255;
    float v;
    if (lr < 2) v = gv[d];
    else        v = (d < 128) ? S[(lr - 2) * 132 + d] : gv[d - 128];
    int gr = (lr == 0) ? b : (lr == 1) ? (16 + b) : (32 + b * 32 + (lr - 2));
    xbf[gr * 256 + d] = f2bf(v);
  }
}

// ---------------------------------------------------------------------------
// Kernel 4: MoE experts — batched MFMA GEMM per expert
// ---------------------------------------------------------------------------
__global__ __launch_bounds__(512) void moe_kernel(
    const unsigned short* __restrict__ xbf, const float* __restrict__ gwt,
    const int* __restrict__ elist, const int* __restrict__ ecnt,
    const unsigned short* __restrict__ w1t, const float* __restrict__ eb1,
    const unsigned short* __restrict__ w2t, const float* __restrict__ eb2,
    float* __restrict__ yall) {
  __shared__ unsigned short Xb[16 * 264];
  __shared__ unsigned short Hb[16 * 520];
  __shared__ float wl[16];
  __shared__ int rowl[16];
  const int e = blockIdx.x >> 3;
  const int slot = blockIdx.x & 7;
  const int n = ecnt[e];
  const int ntiles = (n + 15) >> 4;
  const int tid = threadIdx.x;
  const int wid = tid >> 6;
  const int lane = tid & 63;
  const int fr = lane & 15;
  const int g = lane >> 4;

  for (int t = slot; t < ntiles; t += 8) {
    if (tid < 16) {
      int idx = t * 16 + tid;
      int id = (idx < n) ? elist[e * 544 + idx] : -1;
      rowl[tid] = (id >= 0) ? (id >> 1) : -1;
      wl[tid] = (id >= 0) ? gwt[id] : 0.f;
    }
    __syncthreads();
    for (int i = tid; i < 512; i += 512) {
      int r = i >> 5, c8 = (i & 31) * 8;
      int row = rowl[r];
      bf16x8 v = {0, 0, 0, 0, 0, 0, 0, 0};
      if (row >= 0) v = *(const bf16x8*)(xbf + row * 256 + c8);
      *(bf16x8*)(Xb + r * 264 + c8) = v;
    }
    __syncthreads();
    bf16x8 Af[8];
#pragma unroll
    for (int kf = 0; kf < 8; ++kf)
      Af[kf] = *(const bf16x8*)(Xb + fr * 264 + kf * 32 + g * 8);
#pragma unroll
    for (int ntl = 0; ntl < 4; ++ntl) {
      int nt = wid * 4 + ntl;
      const unsigned short* bp = w1t + (e * 512 + nt * 16 + fr) * 256;
      f32x4 acc = {0.f, 0.f, 0.f, 0.f};
#pragma unroll
      for (int kf = 0; kf < 8; ++kf)
        acc = __builtin_amdgcn_mfma_f32_16x16x32_bf16(Af[kf], *(const bf16x8*)(bp + kf * 32 + g * 8), acc, 0, 0, 0);
      int h = nt * 16 + fr;
      float b1v = eb1[e * 512 + h];
#pragma unroll
      for (int j = 0; j < 4; ++j)
        Hb[(g * 4 + j) * 520 + h] = f2bf(fmaxf(acc[j] + b1v, 0.f));
    }
    __syncthreads();
    {
      const unsigned short* bp = w2t + (e * 128 + wid * 16 + fr) * 512;
      f32x4 acc = {0.f, 0.f, 0.f, 0.f};
#pragma unroll
      for (int kf = 0; kf < 16; ++kf) {
        bf16x8 Ah = *(const bf16x8*)(Hb + fr * 520 + kf * 32 + g * 8);
        acc = __builtin_amdgcn_mfma_f32_16x16x32_bf16(Ah, *(const bf16x8*)(bp + kf * 32 + g * 8), acc, 0, 0, 0);
      }
      int o = wid * 16 + fr;
      float b2v = eb2[e * 128 + o];
#pragma unroll
      for (int j = 0; j < 4; ++j) {
        int r = g * 4 + j;
        int row = rowl[r];
        if (row >= 0) atomicAdd(&yall[row * 128 + o], wl[r] * (acc[j] + b2v));
      }
    }
    __syncthreads();
  }
}

// ---------------------------------------------------------------------------
// Kernel 5: output heads -> fp32 output
// ---------------------------------------------------------------------------
__global__ __launch_bounds__(192) void heads_kernel(
    const float* __restrict__ x, const float* __restrict__ mask,
    const float* __restrict__ pooledws, const float* __restrict__ ctxws,
    const float* __restrict__ yf, const float* __restrict__ yfail, const float* __restrict__ yrca,
    const float* __restrict__ pw, const float* __restrict__ pb,
    const float* __restrict__ fw, const float* __restrict__ fb,
    const float* __restrict__ rw, const float* __restrict__ rb,
    float* __restrict__ out) {
  __shared__ float yfb[128];
  int b = blockIdx.x, t = threadIdx.x;
  if (t < 128) yfb[t] = yf[b * 128 + t];
  __syncthreads();
  if (t < 96) {
    int mm = t / 3, o = t - mm * 3;
    int s = b * 32 + mm;
    float a = pb[o];
    const float* pl = pooledws + s * 64;
    for (int i = 0; i < 64; ++i) a = fmaf(pl[i], pw[i * 3 + o], a);
    const float* cx = ctxws + s * 128;
    for (int i = 0; i < 128; ++i) a = fmaf(cx[i], pw[(64 + i) * 3 + o], a);
    for (int i = 0; i < 128; ++i) a = fmaf(yfb[i], pw[(192 + i) * 3 + o], a);
    a += x[(b * 512 + 511) * 32 + mm] * mask[b * 32 + mm];
    out[b * 131 + t] = a;
  } else if (t < 99) {
    int o = t - 96;
    float a = fb[o];
    const float* yl = yfail + b * 128;
    for (int i = 0; i < 128; ++i) a = fmaf(yl[i], fw[i * 3 + o], a);
    out[b * 131 + 96 + o] = a;
  } else if (t < 131) {
    int mm = t - 99;
    int s = b * 32 + mm;
    float a = rb[0];
    const float* pl = pooledws + s * 64;
    for (int i = 0; i < 64; ++i) a = fmaf(pl[i], rw[i], a);
    const float* cx = ctxws + s * 128;
    for (int i = 0; i < 128; ++i) a = fmaf(cx[i], rw[64 + i], a);
    const float* yr = yrca + s * 128;
    for (int i = 0; i < 128; ++i) a = fmaf(yr[i], rw[192 + i], a);
    out[b * 131 + 99 + mm] = a;
  }
}

// ---------------------------------------------------------------------------
extern "C" void kernel_launch(void* const* d_in, const int* in_sizes, int n_in,
                              void* d_out, int out_size, void* d_ws, size_t ws_size,
                              hipStream_t stream) {
  (void)in_sizes; (void)n_in; (void)out_size; (void)ws_size;
  const float* x    = (const float*)d_in[0];
  const float* msk  = (const float*)d_in[1];
  const float* epw  = (const float*)d_in[2];
  const float* epb  = (const float*)d_in[3];
  const float* tw1  = (const float*)d_in[4];
  const float* tb1  = (const float*)d_in[5];
  const float* tw2  = (const float*)d_in[6];
  const float* tb2  = (const float*)d_in[7];
  const float* eng  = (const float*)d_in[8];
  const float* enb  = (const float*)d_in[9];
  const float* ppw  = (const float*)d_in[10];
  const float* ppb  = (const float*)d_in[11];
  const float* pos  = (const float*)d_in[12];
  const float* twq  = (const float*)d_in[13];
  const float* tbq  = (const float*)d_in[14];
  const float* twk  = (const float*)d_in[15];
  const float* tbk  = (const float*)d_in[16];
  const float* twv  = (const float*)d_in[17];
  const float* tbv  = (const float*)d_in[18];
  const float* two  = (const float*)d_in[19];
  const float* tbo  = (const float*)d_in[20];
  const float* l1g  = (const float*)d_in[21];
  const float* l1b  = (const float*)d_in[22];
  const float* l2g  = (const float*)d_in[23];
  const float* l2b  = (const float*)d_in[24];
  const float* f1w  = (const float*)d_in[25];
  const float* f1b  = (const float*)d_in[26];
  const float* f2w  = (const float*)d_in[27];
  const float* f2b  = (const float*)d_in[28];
  const float* tog  = (const float*)d_in[29];
  const float* tob  = (const float*)d_in[30];
  const float* ew1  = (const float*)d_in[31];
  const float* eb1  = (const float*)d_in[32];
  const float* ew2  = (const float*)d_in[33];
  const float* eb2  = (const float*)d_in[34];
  const float* gfw  = (const float*)d_in[35];
  const float* gfb  = (const float*)d_in[36];
  const float* glw  = (const float*)d_in[37];
  const float* glb  = (const float*)d_in[38];
  const float* grw  = (const float*)d_in[39];
  const float* grb  = (const float*)d_in[40];
  const float* prw  = (const float*)d_in[41];
  const float* prb  = (const float*)d_in[42];
  const float* fw   = (const float*)d_in[43];
  const float* fb   = (const float*)d_in[44];
  const float* rw   = (const float*)d_in[45];
  const float* rb   = (const float*)d_in[46];

  float* ws      = (float*)d_ws;
  float* psum2   = ws;                     // 65536
  float* pooledw = psum2 + 65536;          // 32768
  float* ctxw    = pooledw + 32768;        // 65536
  float* yall    = ctxw + 65536;           // 69632
  float* gwt     = yall + 69632;           // 1088
  int*   ecnt    = (int*)(gwt + 1088);     // 16
  int*   elist   = ecnt + 16;              // 8704
  float* peT     = (float*)(elist + 8704); // 32768
  unsigned short* wpack = (unsigned short*)(peT + 32768);  // 98304
  unsigned short* xfw   = wpack + 98304;                   // 270336
  unsigned short* w1t   = xfw + 270336;                    // 2097152
  unsigned short* w2t   = w1t + 2097152;                   // 1048576
  unsigned short* xbf   = w2t + 1048576;                   // 139264

  const int tcn_lds = (2 * ROWS2 * LDW + 2 * 192 * LDW) * 2 + 1536 * 4;  // 141312 B
  const int xf_lds  = (4224 + 12672 + 8448 + 512 + 64) * 4 + (2 * 4352 + 8448) * 2;  // 137824 B
  hipFuncSetAttribute((const void*)tcn_kernel, hipFuncAttributeMaxDynamicSharedMemorySize, tcn_lds);
  hipFuncSetAttribute((const void*)xf_kernel,  hipFuncAttributeMaxDynamicSharedMemorySize, xf_lds);

  prep_kernel<<<911, 256, 0, stream>>>(ppw, twq, twk, twv, two, f1w, f2w, ew1, ew2,
                                       tw1, tw2, xfw, w1t, w2t, wpack, peT, yall, ecnt);
  tcn_kernel<<<1024, 1024, tcn_lds, stream>>>(x, msk, epw, epb, wpack, tb1, tb2, peT,
                                              eng, enb, psum2);
  xf_kernel<<<16, 1024, xf_lds, stream>>>(psum2, msk, xfw, ppb, pos,
                                          tbq, tbk, tbv, tbo,
                                          l1g, l1b, l2g, l2b, f1b, f2b,
                                          tog, tob,
                                          gfw, gfb, glw, glb, grw, grb,
                                          pooledw, ctxw, gwt, ecnt, elist, xbf);
  moe_kernel<<<128, 512, 0, stream>>>(xbf, gwt, elist, ecnt, w1t, eb1, w2t, eb2, yall);
  heads_kernel<<<16, 192, 0, stream>>>(x, msk, pooledw, ctxw,
                                       yall, yall + 2048, yall + 4096,
                                       prw, prb, fw, fb, rw, rb, (float*)d_out);
}